// Round 1
// baseline (18777.673 us; speedup 1.0000x reference)
//
#include <hip/hip_runtime.h>
#include <cstdint>
#include <cstddef>

#define NNODES 100000
#define NEDGES 1600000
#define ETOT   (NEDGES + NNODES)
#define IN_DIM 20
#define HID    32
#define HEADS  4
#define HC1    128
#define OUTC   64
#define NEG    0.2f

// ---- float <-> monotone unsigned key (for atomicMax on floats) ----
__device__ __forceinline__ unsigned f2key(float f) {
    unsigned b = __float_as_uint(f);
    return (b & 0x80000000u) ? ~b : (b | 0x80000000u);
}
__device__ __forceinline__ float key2f(unsigned k) {
    unsigned b = (k & 0x80000000u) ? (k ^ 0x80000000u) : ~k;
    return __uint_as_float(b);
}
__device__ __forceinline__ float lrelu(float v) { return v >= 0.0f ? v : NEG * v; }

// ---- sum of edge_attr (for self-loop fill value) ----
__global__ void k_sum(const float* __restrict__ ea, int n, float* __restrict__ out) {
    float s = 0.0f;
    for (int i = blockIdx.x * blockDim.x + threadIdx.x; i < n; i += gridDim.x * blockDim.x)
        s += ea[i];
    #pragma unroll
    for (int off = 32; off > 0; off >>= 1) s += __shfl_down(s, off, 64);
    __shared__ float ls[4];
    int lane = threadIdx.x & 63, wid = threadIdx.x >> 6;
    if (lane == 0) ls[wid] = s;
    __syncthreads();
    if (threadIdx.x == 0) {
        float t = ls[0] + ls[1] + ls[2] + ls[3];
        atomicAdd(out, t);
    }
}

// ---- layer 1 node transforms: xl = x@Wl^T+bl, xr = x@Wr^T+br  (K=20, M=128) ----
__global__ void k_lin1(const float* __restrict__ x,
                       const float* __restrict__ Wl, const float* __restrict__ bl,
                       const float* __restrict__ Wr, const float* __restrict__ br,
                       float* __restrict__ xl, float* __restrict__ xr) {
    int n = blockIdx.x;
    int col = threadIdx.x;  // 0..127
    __shared__ float xs[IN_DIM];
    if (col < IN_DIM) xs[col] = x[(size_t)n * IN_DIM + col];
    __syncthreads();
    float al = bl[col], ar = br[col];
    const float* wl = Wl + (size_t)col * IN_DIM;
    const float* wr = Wr + (size_t)col * IN_DIM;
    #pragma unroll
    for (int k = 0; k < IN_DIM; ++k) {
        al += xs[k] * wl[k];
        ar += xs[k] * wr[k];
    }
    xl[(size_t)n * HC1 + col] = al;
    xr[(size_t)n * HC1 + col] = ar;
}

// ---- layer 1 edge pass A: logits + segment max. one thread per (edge, head) ----
__global__ void k_edgeA1(const int* __restrict__ ei, const float* __restrict__ ea,
                         const float* __restrict__ easum,
                         const float* __restrict__ xl, const float* __restrict__ xr,
                         const float* __restrict__ We, const float* __restrict__ att,
                         float* __restrict__ logits, unsigned* __restrict__ mx) {
    __shared__ float Wes[HC1], atts[HC1];
    int tid = threadIdx.x;
    if (tid < HC1) Wes[tid] = We[tid];
    else atts[tid - HC1] = att[tid - HC1];
    __syncthreads();
    int t = blockIdx.x * blockDim.x + tid;
    if (t >= ETOT * HEADS) return;
    int e = t >> 2, h = t & 3;
    int src, dst; float a;
    if (e < NEDGES) { src = ei[e]; dst = ei[NEDGES + e]; a = ea[e]; }
    else { src = dst = e - NEDGES; a = easum[0] * (1.0f / (float)NEDGES); }
    const float4* pl = (const float4*)(xl + (size_t)src * HC1 + h * HID);
    const float4* pr = (const float4*)(xr + (size_t)dst * HC1 + h * HID);
    const float4* pw = (const float4*)(Wes + h * HID);
    const float4* pa = (const float4*)(atts + h * HID);
    float lg = 0.0f;
    #pragma unroll
    for (int i = 0; i < HID / 4; ++i) {
        float4 l = pl[i], r = pr[i], w = pw[i], at = pa[i];
        lg += lrelu(l.x + r.x + a * w.x) * at.x;
        lg += lrelu(l.y + r.y + a * w.y) * at.y;
        lg += lrelu(l.z + r.z + a * w.z) * at.z;
        lg += lrelu(l.w + r.w + a * w.w) * at.w;
    }
    logits[t] = lg;
    atomicMax(mx + (size_t)dst * HEADS + h, f2key(lg));
}

// ---- layer 1 edge pass B: exp, denom, weighted scatter. one thread per (edge, head) ----
__global__ void k_edgeB1(const int* __restrict__ ei,
                         const float* __restrict__ xl, const float* __restrict__ logits,
                         const unsigned* __restrict__ mx,
                         float* __restrict__ denom, float* __restrict__ agg) {
    int t = blockIdx.x * blockDim.x + threadIdx.x;
    if (t >= ETOT * HEADS) return;
    int e = t >> 2, h = t & 3;
    int src, dst;
    if (e < NEDGES) { src = ei[e]; dst = ei[NEDGES + e]; }
    else src = dst = e - NEDGES;
    float m = key2f(mx[(size_t)dst * HEADS + h]);
    float ex = __expf(logits[t] - m);
    atomicAdd(denom + (size_t)dst * HEADS + h, ex);
    const float4* pl = (const float4*)(xl + (size_t)src * HC1 + h * HID);
    float* pa = agg + (size_t)dst * HC1 + h * HID;
    #pragma unroll
    for (int i = 0; i < HID / 4; ++i) {
        float4 l = pl[i];
        atomicAdd(pa + 4 * i + 0, ex * l.x);
        atomicAdd(pa + 4 * i + 1, ex * l.y);
        atomicAdd(pa + 4 * i + 2, ex * l.z);
        atomicAdd(pa + 4 * i + 3, ex * l.w);
    }
}

// ---- layer 1 finalize: divide by denom, +bias, ELU ----
__global__ void k_fin1(const float* __restrict__ agg, const float* __restrict__ denom,
                       const float* __restrict__ b, float* __restrict__ h1) {
    int t = blockIdx.x * blockDim.x + threadIdx.x;
    if (t >= NNODES * HC1) return;
    int n = t >> 7, col = t & 127;
    float v = agg[t] / denom[(size_t)n * HEADS + (col >> 5)] + b[col];
    h1[t] = v > 0.0f ? v : expm1f(v);
}

// ---- layer 2 node transforms (K=128, M=64): 4 nodes per block ----
__global__ void k_lin2(const float* __restrict__ h1,
                       const float* __restrict__ Wl, const float* __restrict__ bl,
                       const float* __restrict__ Wr, const float* __restrict__ br,
                       float* __restrict__ xl2, float* __restrict__ xr2) {
    __shared__ float hs[4 * HC1];
    int nb = blockIdx.x * 4;
    int tid = threadIdx.x;
    hs[tid]       = h1[(size_t)nb * HC1 + tid];
    hs[tid + 256] = h1[(size_t)nb * HC1 + 256 + tid];
    __syncthreads();
    int nl = tid >> 6, col = tid & 63;
    float al = bl[col], ar = br[col];
    const float4* wl = (const float4*)(Wl + (size_t)col * HC1);
    const float4* wr = (const float4*)(Wr + (size_t)col * HC1);
    const float4* hv = (const float4*)(hs + nl * HC1);
    #pragma unroll
    for (int i = 0; i < HC1 / 4; ++i) {
        float4 h4 = hv[i], w4 = wl[i], v4 = wr[i];
        al += h4.x * w4.x + h4.y * w4.y + h4.z * w4.z + h4.w * w4.w;
        ar += h4.x * v4.x + h4.y * v4.y + h4.z * v4.z + h4.w * v4.w;
    }
    xl2[(size_t)(nb + nl) * OUTC + col] = al;
    xr2[(size_t)(nb + nl) * OUTC + col] = ar;
}

// ---- layer 2 edge pass A: one thread per edge (H=1) ----
__global__ void k_edgeA2(const int* __restrict__ ei, const float* __restrict__ ea,
                         const float* __restrict__ easum,
                         const float* __restrict__ xl2, const float* __restrict__ xr2,
                         const float* __restrict__ We, const float* __restrict__ att,
                         float* __restrict__ logits2, unsigned* __restrict__ mx2) {
    __shared__ float Wes[OUTC], atts[OUTC];
    int tid = threadIdx.x;
    if (tid < OUTC) Wes[tid] = We[tid];
    else if (tid < 2 * OUTC) atts[tid - OUTC] = att[tid - OUTC];
    __syncthreads();
    int e = blockIdx.x * blockDim.x + tid;
    if (e >= ETOT) return;
    int src, dst; float a;
    if (e < NEDGES) { src = ei[e]; dst = ei[NEDGES + e]; a = ea[e]; }
    else { src = dst = e - NEDGES; a = easum[0] * (1.0f / (float)NEDGES); }
    const float4* pl = (const float4*)(xl2 + (size_t)src * OUTC);
    const float4* pr = (const float4*)(xr2 + (size_t)dst * OUTC);
    const float4* pw = (const float4*)Wes;
    const float4* pa = (const float4*)atts;
    float lg = 0.0f;
    #pragma unroll
    for (int i = 0; i < OUTC / 4; ++i) {
        float4 l = pl[i], r = pr[i], w = pw[i], at = pa[i];
        lg += lrelu(l.x + r.x + a * w.x) * at.x;
        lg += lrelu(l.y + r.y + a * w.y) * at.y;
        lg += lrelu(l.z + r.z + a * w.z) * at.z;
        lg += lrelu(l.w + r.w + a * w.w) * at.w;
    }
    logits2[e] = lg;
    atomicMax(mx2 + dst, f2key(lg));
}

// ---- layer 2 edge pass B ----
__global__ void k_edgeB2(const int* __restrict__ ei,
                         const float* __restrict__ xl2, const float* __restrict__ logits2,
                         const unsigned* __restrict__ mx2,
                         float* __restrict__ denom2, float* __restrict__ agg2) {
    int e = blockIdx.x * blockDim.x + threadIdx.x;
    if (e >= ETOT) return;
    int src, dst;
    if (e < NEDGES) { src = ei[e]; dst = ei[NEDGES + e]; }
    else src = dst = e - NEDGES;
    float m = key2f(mx2[dst]);
    float ex = __expf(logits2[e] - m);
    atomicAdd(denom2 + dst, ex);
    const float4* pl = (const float4*)(xl2 + (size_t)src * OUTC);
    float* pa = agg2 + (size_t)dst * OUTC;
    #pragma unroll
    for (int i = 0; i < OUTC / 4; ++i) {
        float4 l = pl[i];
        atomicAdd(pa + 4 * i + 0, ex * l.x);
        atomicAdd(pa + 4 * i + 1, ex * l.y);
        atomicAdd(pa + 4 * i + 2, ex * l.z);
        atomicAdd(pa + 4 * i + 3, ex * l.w);
    }
}

// ---- layer 2 finalize ----
__global__ void k_fin2(const float* __restrict__ agg2, const float* __restrict__ denom2,
                       const float* __restrict__ b, float* __restrict__ out) {
    int t = blockIdx.x * blockDim.x + threadIdx.x;
    if (t >= NNODES * OUTC) return;
    int n = t >> 6, c = t & 63;
    out[t] = agg2[t] / denom2[n] + b[c];
}

extern "C" void kernel_launch(void* const* d_in, const int* in_sizes, int n_in,
                              void* d_out, int out_size, void* d_ws, size_t ws_size,
                              hipStream_t stream) {
    (void)in_sizes; (void)n_in; (void)out_size; (void)ws_size;
    const float* x    = (const float*)d_in[0];
    const int*   ei   = (const int*)d_in[1];
    const float* ea   = (const float*)d_in[2];
    const float* Wl1  = (const float*)d_in[3];
    const float* bl1  = (const float*)d_in[4];
    const float* Wr1  = (const float*)d_in[5];
    const float* br1  = (const float*)d_in[6];
    const float* We1  = (const float*)d_in[7];
    const float* att1 = (const float*)d_in[8];
    const float* b1   = (const float*)d_in[9];
    const float* Wl2  = (const float*)d_in[10];
    const float* bl2  = (const float*)d_in[11];
    const float* Wr2  = (const float*)d_in[12];
    const float* br2  = (const float*)d_in[13];
    const float* We2  = (const float*)d_in[14];
    const float* att2 = (const float*)d_in[15];
    const float* b2   = (const float*)d_in[16];
    float* out = (float*)d_out;

    // workspace layout (floats)
    float* ws = (float*)d_ws;
    size_t off = 0;
    float* xl     = ws + off; off += (size_t)NNODES * HC1;   // 12.8M
    float* xr     = ws + off; off += (size_t)NNODES * HC1;
    float* agg    = ws + off; off += (size_t)NNODES * HC1;
    float* h1     = ws + off; off += (size_t)NNODES * HC1;
    float* logits = ws + off; off += (size_t)ETOT * HEADS;   // 6.8M
    unsigned* mx  = (unsigned*)(ws + off); off += (size_t)NNODES * HEADS;
    float* denom  = ws + off; off += (size_t)NNODES * HEADS;
    float* easum  = ws + off; off += 1;

    // ---- layer 1 ----
    hipMemsetAsync(easum, 0, sizeof(float), stream);
    hipMemsetAsync(mx, 0, (size_t)NNODES * HEADS * 4, stream);
    hipMemsetAsync(denom, 0, (size_t)NNODES * HEADS * 4, stream);
    hipMemsetAsync(agg, 0, (size_t)NNODES * HC1 * 4, stream);

    k_sum<<<256, 256, 0, stream>>>(ea, NEDGES, easum);
    k_lin1<<<NNODES, 128, 0, stream>>>(x, Wl1, bl1, Wr1, br1, xl, xr);
    int tA1 = ETOT * HEADS;
    k_edgeA1<<<(tA1 + 255) / 256, 256, 0, stream>>>(ei, ea, easum, xl, xr, We1, att1, logits, mx);
    k_edgeB1<<<(tA1 + 255) / 256, 256, 0, stream>>>(ei, xl, logits, mx, denom, agg);
    k_fin1<<<(NNODES * HC1 + 255) / 256, 256, 0, stream>>>(agg, denom, b1, h1);

    // ---- layer 2 (reuses layer-1 buffers; all prior readers are done) ----
    float* xl2 = xl; float* xr2 = xr; float* agg2 = agg; float* logits2 = logits;
    unsigned* mx2 = mx; float* denom2 = denom;
    hipMemsetAsync(mx2, 0, (size_t)NNODES * 4, stream);
    hipMemsetAsync(denom2, 0, (size_t)NNODES * 4, stream);
    hipMemsetAsync(agg2, 0, (size_t)NNODES * OUTC * 4, stream);

    k_lin2<<<NNODES / 4, 256, 0, stream>>>(h1, Wl2, bl2, Wr2, br2, xl2, xr2);
    k_edgeA2<<<(ETOT + 255) / 256, 256, 0, stream>>>(ei, ea, easum, xl2, xr2, We2, att2, logits2, mx2);
    k_edgeB2<<<(ETOT + 255) / 256, 256, 0, stream>>>(ei, xl2, logits2, mx2, denom2, agg2);
    k_fin2<<<(NNODES * OUTC + 255) / 256, 256, 0, stream>>>(agg2, denom2, b2, out);
}

// Round 2
// 1398.599 us; speedup vs baseline: 13.4261x; 13.4261x over previous
//
#include <hip/hip_runtime.h>
#include <cstdint>
#include <cstddef>

#define NNODES 100000
#define NEDGES 1600000
#define IN_DIM 20
#define HID    32
#define HEADS  4
#define HC1    128
#define OUTC   64
#define NEG    0.2f
#define NCHUNK ((NNODES + 255) / 256)   // 391

__device__ __forceinline__ float lrelu(float v) { return v >= 0.0f ? v : NEG * v; }

// ---- sum of edge_attr (for self-loop fill value) ----
__global__ void k_sum(const float* __restrict__ ea, int n, float* __restrict__ out) {
    float s = 0.0f;
    for (int i = blockIdx.x * blockDim.x + threadIdx.x; i < n; i += gridDim.x * blockDim.x)
        s += ea[i];
    #pragma unroll
    for (int off = 32; off > 0; off >>= 1) s += __shfl_down(s, off, 64);
    __shared__ float ls[4];
    int lane = threadIdx.x & 63, wid = threadIdx.x >> 6;
    if (lane == 0) ls[wid] = s;
    __syncthreads();
    if (threadIdx.x == 0) {
        float t = ls[0] + ls[1] + ls[2] + ls[3];
        atomicAdd(out, t);
    }
}

// ================= CSR build (by destination) =================
__global__ void k_hist(const int* __restrict__ ei, int* __restrict__ cnt) {
    int e = blockIdx.x * blockDim.x + threadIdx.x;
    if (e < NEDGES) atomicAdd(&cnt[ei[NEDGES + e]], 1);
}

// per-chunk exclusive scan (chunk = 256) + chunk totals
__global__ void k_scan_chunk(const int* __restrict__ cnt, int* __restrict__ rowptr,
                             int* __restrict__ csums) {
    __shared__ int s[256];
    int i = blockIdx.x * 256 + threadIdx.x;
    int v = (i < NNODES) ? cnt[i] : 0;
    s[threadIdx.x] = v;
    __syncthreads();
    for (int off = 1; off < 256; off <<= 1) {
        int t = (threadIdx.x >= off) ? s[threadIdx.x - off] : 0;
        __syncthreads();
        s[threadIdx.x] += t;
        __syncthreads();
    }
    if (i < NNODES) rowptr[i] = s[threadIdx.x] - v;   // chunk-local exclusive
    if (threadIdx.x == 255) csums[blockIdx.x] = s[255];
}

// single-block exclusive scan of chunk totals (NCHUNK=391 <= 512)
__global__ void k_scan_tops(int* __restrict__ csums) {
    __shared__ int s[512];
    int v = (threadIdx.x < NCHUNK) ? csums[threadIdx.x] : 0;
    s[threadIdx.x] = v;
    __syncthreads();
    for (int off = 1; off < 512; off <<= 1) {
        int t = (threadIdx.x >= off) ? s[threadIdx.x - off] : 0;
        __syncthreads();
        s[threadIdx.x] += t;
        __syncthreads();
    }
    if (threadIdx.x < NCHUNK) csums[threadIdx.x] = s[threadIdx.x] - v;  // exclusive base
}

__global__ void k_scan_add(int* __restrict__ rowptr, const int* __restrict__ csums) {
    int i = blockIdx.x * 256 + threadIdx.x;
    if (i < NNODES) rowptr[i] += csums[blockIdx.x];
    if (i == 0) rowptr[NNODES] = NEDGES;
}

__global__ void k_scatter(const int* __restrict__ ei, const float* __restrict__ ea,
                          const int* __restrict__ rowptr, int* __restrict__ fill,
                          int* __restrict__ csrc, float* __restrict__ cea) {
    int e = blockIdx.x * blockDim.x + threadIdx.x;
    if (e >= NEDGES) return;
    int dst = ei[NEDGES + e];
    int pos = rowptr[dst] + atomicAdd(&fill[dst], 1);
    csrc[pos] = ei[e];
    cea[pos] = ea[e];
}

// ================= node transforms =================
// layer 1: xl = x@Wl^T+bl, xr = x@Wr^T+br  (K=20, M=128)
__global__ void k_lin1(const float* __restrict__ x,
                       const float* __restrict__ Wl, const float* __restrict__ bl,
                       const float* __restrict__ Wr, const float* __restrict__ br,
                       float* __restrict__ xl, float* __restrict__ xr) {
    int n = blockIdx.x;
    int col = threadIdx.x;  // 0..127
    __shared__ float xs[IN_DIM];
    if (col < IN_DIM) xs[col] = x[(size_t)n * IN_DIM + col];
    __syncthreads();
    float al = bl[col], ar = br[col];
    const float* wl = Wl + (size_t)col * IN_DIM;
    const float* wr = Wr + (size_t)col * IN_DIM;
    #pragma unroll
    for (int k = 0; k < IN_DIM; ++k) {
        al += xs[k] * wl[k];
        ar += xs[k] * wr[k];
    }
    xl[(size_t)n * HC1 + col] = al;
    xr[(size_t)n * HC1 + col] = ar;
}

// layer 2: (K=128, M=64): 4 nodes per block
__global__ void k_lin2(const float* __restrict__ h1,
                       const float* __restrict__ Wl, const float* __restrict__ bl,
                       const float* __restrict__ Wr, const float* __restrict__ br,
                       float* __restrict__ xl2, float* __restrict__ xr2) {
    __shared__ float hs[4 * HC1];
    int nb = blockIdx.x * 4;
    int tid = threadIdx.x;
    hs[tid]       = h1[(size_t)nb * HC1 + tid];
    hs[tid + 256] = h1[(size_t)nb * HC1 + 256 + tid];
    __syncthreads();
    int nl = tid >> 6, col = tid & 63;
    float al = bl[col], ar = br[col];
    const float4* wl = (const float4*)(Wl + (size_t)col * HC1);
    const float4* wr = (const float4*)(Wr + (size_t)col * HC1);
    const float4* hv = (const float4*)(hs + nl * HC1);
    #pragma unroll
    for (int i = 0; i < HC1 / 4; ++i) {
        float4 h4 = hv[i], w4 = wl[i], v4 = wr[i];
        al += h4.x * w4.x + h4.y * w4.y + h4.z * w4.z + h4.w * w4.w;
        ar += h4.x * v4.x + h4.y * v4.y + h4.z * v4.z + h4.w * v4.w;
    }
    xl2[(size_t)(nb + nl) * OUTC + col] = al;
    xr2[(size_t)(nb + nl) * OUTC + col] = ar;
}

// ================= fused per-node edge kernels (online softmax) =================
// layer 1: one wave per node; lane holds channels {2*lane, 2*lane+1}; head = lane>>4
__global__ void k_node1(const int* __restrict__ rowptr, const int* __restrict__ csrc,
                        const float* __restrict__ cea, const float* __restrict__ easum,
                        const float* __restrict__ xl, const float* __restrict__ xr,
                        const float* __restrict__ We, const float* __restrict__ att,
                        const float* __restrict__ bias, float* __restrict__ h1) {
    int n = blockIdx.x * 4 + (threadIdx.x >> 6);
    int lane = threadIdx.x & 63;
    if (n >= NNODES) return;
    int c = lane * 2;
    float2 xrd = *(const float2*)(xr + (size_t)n * HC1 + c);
    float2 we  = *(const float2*)(We + c);
    float2 at  = *(const float2*)(att + c);
    float m = -1e30f, s = 0.f, acc0 = 0.f, acc1 = 0.f;
    int start = rowptr[n], end = rowptr[n + 1];
    float amean = easum[0] * (1.0f / (float)NEDGES);
    // neighbors in chunks of <=64, plus one virtual self edge at index `end`
    for (int base = start; base < end + 1; base += 64) {
        int rem = end + 1 - base;
        int cnt_ = rem < 64 ? rem : 64;
        int idx = base + lane;
        int sl = 0; float al = 0.f;
        if (lane < cnt_) {
            if (idx < end) { sl = csrc[idx]; al = cea[idx]; }
            else           { sl = n;         al = amean;    }
        }
        for (int j = 0; j < cnt_; ++j) {
            int   src = __shfl(sl, j, 64);
            float a   = __shfl(al, j, 64);
            float2 xs = *(const float2*)(xl + (size_t)src * HC1 + c);
            float e0 = lrelu(xs.x + xrd.x + a * we.x);
            float e1 = lrelu(xs.y + xrd.y + a * we.y);
            float p = e0 * at.x + e1 * at.y;
            // reduce over the 16 lanes of this head
            p += __shfl_xor(p, 1, 64);
            p += __shfl_xor(p, 2, 64);
            p += __shfl_xor(p, 4, 64);
            p += __shfl_xor(p, 8, 64);
            float mn = fmaxf(m, p);
            float sc = __expf(m - mn);
            float pe = __expf(p - mn);
            s    = s * sc + pe;
            acc0 = acc0 * sc + pe * xs.x;
            acc1 = acc1 * sc + pe * xs.y;
            m = mn;
        }
    }
    float inv = 1.0f / s;
    float v0 = acc0 * inv + bias[c];
    float v1 = acc1 * inv + bias[c + 1];
    v0 = v0 > 0.f ? v0 : expm1f(v0);   // ELU fused
    v1 = v1 > 0.f ? v1 : expm1f(v1);
    *(float2*)(h1 + (size_t)n * HC1 + c) = make_float2(v0, v1);
}

// layer 2: one wave per node; lane = channel (64); single head
__global__ void k_node2(const int* __restrict__ rowptr, const int* __restrict__ csrc,
                        const float* __restrict__ cea, const float* __restrict__ easum,
                        const float* __restrict__ xl2, const float* __restrict__ xr2,
                        const float* __restrict__ We, const float* __restrict__ att,
                        const float* __restrict__ bias, float* __restrict__ out) {
    int n = blockIdx.x * 4 + (threadIdx.x >> 6);
    int lane = threadIdx.x & 63;
    if (n >= NNODES) return;
    float xrd = xr2[(size_t)n * OUTC + lane];
    float we  = We[lane];
    float at  = att[lane];
    float m = -1e30f, s = 0.f, acc = 0.f;
    int start = rowptr[n], end = rowptr[n + 1];
    float amean = easum[0] * (1.0f / (float)NEDGES);
    for (int base = start; base < end + 1; base += 64) {
        int rem = end + 1 - base;
        int cnt_ = rem < 64 ? rem : 64;
        int idx = base + lane;
        int sl = 0; float al = 0.f;
        if (lane < cnt_) {
            if (idx < end) { sl = csrc[idx]; al = cea[idx]; }
            else           { sl = n;         al = amean;    }
        }
        for (int j = 0; j < cnt_; ++j) {
            int   src = __shfl(sl, j, 64);
            float a   = __shfl(al, j, 64);
            float xs = xl2[(size_t)src * OUTC + lane];
            float p = lrelu(xs + xrd + a * we) * at;
            p += __shfl_xor(p, 1, 64);
            p += __shfl_xor(p, 2, 64);
            p += __shfl_xor(p, 4, 64);
            p += __shfl_xor(p, 8, 64);
            p += __shfl_xor(p, 16, 64);
            p += __shfl_xor(p, 32, 64);
            float mn = fmaxf(m, p);
            float sc = __expf(m - mn);
            float pe = __expf(p - mn);
            s   = s * sc + pe;
            acc = acc * sc + pe * xs;
            m = mn;
        }
    }
    out[(size_t)n * OUTC + lane] = acc / s + bias[lane];
}

extern "C" void kernel_launch(void* const* d_in, const int* in_sizes, int n_in,
                              void* d_out, int out_size, void* d_ws, size_t ws_size,
                              hipStream_t stream) {
    (void)in_sizes; (void)n_in; (void)out_size; (void)ws_size;
    const float* x    = (const float*)d_in[0];
    const int*   ei   = (const int*)d_in[1];
    const float* ea   = (const float*)d_in[2];
    const float* Wl1  = (const float*)d_in[3];
    const float* bl1  = (const float*)d_in[4];
    const float* Wr1  = (const float*)d_in[5];
    const float* br1  = (const float*)d_in[6];
    const float* We1  = (const float*)d_in[7];
    const float* att1 = (const float*)d_in[8];
    const float* b1   = (const float*)d_in[9];
    const float* Wl2  = (const float*)d_in[10];
    const float* bl2  = (const float*)d_in[11];
    const float* Wr2  = (const float*)d_in[12];
    const float* br2  = (const float*)d_in[13];
    const float* We2  = (const float*)d_in[14];
    const float* att2 = (const float*)d_in[15];
    const float* b2   = (const float*)d_in[16];
    float* out = (float*)d_out;

    // ---- workspace layout (floats/ints) ----
    float* ws = (float*)d_ws;
    size_t off = 0;
    float* xl     = ws + off; off += (size_t)NNODES * HC1;    // 12.8M
    float* xr     = ws + off; off += (size_t)NNODES * HC1;
    float* h1     = ws + off; off += (size_t)NNODES * HC1;
    int*   csrc   = (int*)(ws + off);   off += NEDGES;        // 1.6M
    float* cea    = ws + off;           off += NEDGES;
    int*   cnt    = (int*)(ws + off);   off += NNODES;
    int*   rowptr = (int*)(ws + off);   off += NNODES + 1;
    int*   fill   = (int*)(ws + off);   off += NNODES;
    int*   csums  = (int*)(ws + off);   off += 512;
    float* easum  = ws + off;           off += 1;
    // layer-2 transforms reuse xl/xr storage (only need N*64 each)
    float* xl2 = xl;
    float* xr2 = xr;

    // ---- zero-init accumulators ----
    hipMemsetAsync(easum, 0, sizeof(float), stream);
    hipMemsetAsync(cnt,  0, (size_t)NNODES * 4, stream);
    hipMemsetAsync(fill, 0, (size_t)NNODES * 4, stream);

    // ---- CSR build (shared by both layers) ----
    k_sum<<<256, 256, 0, stream>>>(ea, NEDGES, easum);
    k_hist<<<(NEDGES + 255) / 256, 256, 0, stream>>>(ei, cnt);
    k_scan_chunk<<<NCHUNK, 256, 0, stream>>>(cnt, rowptr, csums);
    k_scan_tops<<<1, 512, 0, stream>>>(csums);
    k_scan_add<<<NCHUNK, 256, 0, stream>>>(rowptr, csums);
    k_scatter<<<(NEDGES + 255) / 256, 256, 0, stream>>>(ei, ea, rowptr, fill, csrc, cea);

    // ---- layer 1 ----
    k_lin1<<<NNODES, 128, 0, stream>>>(x, Wl1, bl1, Wr1, br1, xl, xr);
    k_node1<<<(NNODES + 3) / 4, 256, 0, stream>>>(rowptr, csrc, cea, easum,
                                                  xl, xr, We1, att1, b1, h1);

    // ---- layer 2 ----
    k_lin2<<<NNODES / 4, 256, 0, stream>>>(h1, Wl2, bl2, Wr2, br2, xl2, xr2);
    k_node2<<<(NNODES + 3) / 4, 256, 0, stream>>>(rowptr, csrc, cea, easum,
                                                  xl2, xr2, We2, att2, b2, out);
}

// Round 3
// 736.095 us; speedup vs baseline: 25.5098x; 1.9000x over previous
//
#include <hip/hip_runtime.h>
#include <cstdint>
#include <cstddef>

#define NNODES 100000
#define NEDGES 1600000
#define IN_DIM 20
#define HID    32
#define HEADS  4
#define HC1    128
#define OUTC   64
#define NEG    0.2f
#define NCHUNK ((NNODES + 255) / 256)   // 391
#define NBLK   ((NNODES + 63) / 64)     // 1563

__device__ __forceinline__ float lrelu(float v) { return v >= 0.0f ? v : NEG * v; }

// ---- sum of edge_attr (for self-loop fill value) ----
__global__ void k_sum(const float* __restrict__ ea, int n, float* __restrict__ out) {
    float s = 0.0f;
    for (int i = blockIdx.x * blockDim.x + threadIdx.x; i < n; i += gridDim.x * blockDim.x)
        s += ea[i];
    #pragma unroll
    for (int off = 32; off > 0; off >>= 1) s += __shfl_down(s, off, 64);
    __shared__ float ls[4];
    int lane = threadIdx.x & 63, wid = threadIdx.x >> 6;
    if (lane == 0) ls[wid] = s;
    __syncthreads();
    if (threadIdx.x == 0) {
        float t = ls[0] + ls[1] + ls[2] + ls[3];
        atomicAdd(out, t);
    }
}

// ================= CSR build (by destination) =================
__global__ void k_hist(const int* __restrict__ ei, int* __restrict__ cnt) {
    int e = blockIdx.x * blockDim.x + threadIdx.x;
    if (e < NEDGES) atomicAdd(&cnt[ei[NEDGES + e]], 1);
}

__global__ void k_scan_chunk(const int* __restrict__ cnt, int* __restrict__ rowptr,
                             int* __restrict__ csums) {
    __shared__ int s[256];
    int i = blockIdx.x * 256 + threadIdx.x;
    int v = (i < NNODES) ? cnt[i] : 0;
    s[threadIdx.x] = v;
    __syncthreads();
    for (int off = 1; off < 256; off <<= 1) {
        int t = (threadIdx.x >= off) ? s[threadIdx.x - off] : 0;
        __syncthreads();
        s[threadIdx.x] += t;
        __syncthreads();
    }
    if (i < NNODES) rowptr[i] = s[threadIdx.x] - v;
    if (threadIdx.x == 255) csums[blockIdx.x] = s[255];
}

__global__ void k_scan_tops(int* __restrict__ csums) {
    __shared__ int s[512];
    int v = (threadIdx.x < NCHUNK) ? csums[threadIdx.x] : 0;
    s[threadIdx.x] = v;
    __syncthreads();
    for (int off = 1; off < 512; off <<= 1) {
        int t = (threadIdx.x >= off) ? s[threadIdx.x - off] : 0;
        __syncthreads();
        s[threadIdx.x] += t;
        __syncthreads();
    }
    if (threadIdx.x < NCHUNK) csums[threadIdx.x] = s[threadIdx.x] - v;
}

__global__ void k_scan_add(int* __restrict__ rowptr, const int* __restrict__ csums) {
    int i = blockIdx.x * 256 + threadIdx.x;
    if (i < NNODES) rowptr[i] += csums[blockIdx.x];
    if (i == 0) rowptr[NNODES] = NEDGES;
}

__global__ void k_scatter(const int* __restrict__ ei, const float* __restrict__ ea,
                          const int* __restrict__ rowptr, int* __restrict__ fill,
                          int* __restrict__ csrc, float* __restrict__ cea) {
    int e = blockIdx.x * blockDim.x + threadIdx.x;
    if (e >= NEDGES) return;
    int dst = ei[NEDGES + e];
    int pos = rowptr[dst] + atomicAdd(&fill[dst], 1);
    csrc[pos] = ei[e];
    cea[pos] = ea[e];
}

// ================= weight prep: Bt[k][c] combined-transposed =================
// layer 1: Bt1 [20][256], c<128 -> Wl1[c][k], else Wr1[c-128][k]
__global__ void k_prepB1(const float* __restrict__ Wl, const float* __restrict__ Wr,
                         float* __restrict__ Bt) {
    int idx = blockIdx.x * 256 + threadIdx.x;   // 5120 total
    if (idx >= 20 * 256) return;
    int k = idx >> 8, c = idx & 255;
    Bt[idx] = (c < 128) ? Wl[c * IN_DIM + k] : Wr[(c - 128) * IN_DIM + k];
}
// layer 2: Bt2 [128][128], c<64 -> Wl2[c][k], else Wr2[c-64][k]
__global__ void k_prepB2(const float* __restrict__ Wl, const float* __restrict__ Wr,
                         float* __restrict__ Bt) {
    int idx = blockIdx.x * 256 + threadIdx.x;   // 16384 total
    if (idx >= 128 * 128) return;
    int k = idx >> 7, c = idx & 127;
    Bt[idx] = (c < 64) ? Wl[c * HC1 + k] : Wr[(c - 64) * HC1 + k];
}

// ================= layer-1 GEMM: [N x 20] @ Bt1 -> xl|xr [N x 128] each ======
// block: 64 nodes x 256 cols; thread: 8 nodes (tn+8i) x 8 cols (tc*8..+7)
__global__ __launch_bounds__(256) void k_gemm1(
        const float* __restrict__ x, const float* __restrict__ Bt,
        const float* __restrict__ bl, const float* __restrict__ br,
        float* __restrict__ xl, float* __restrict__ xr) {
    __shared__ float sA[64 * IN_DIM];     // 5120 floats, flat stride 20
    __shared__ float sB[IN_DIM * 256];    // 5120 floats
    int nb = blockIdx.x * 64;
    int tid = threadIdx.x;
    // stage A: contiguous 1280 floats from x (clamped at tail)
    {
        size_t base = (size_t)nb * IN_DIM;
        size_t maxf = (size_t)NNODES * IN_DIM;
        for (int f = tid * 4; f < 64 * IN_DIM; f += 1024) {
            float4 v;
            if (base + f + 4 <= maxf) v = *(const float4*)(x + base + f);
            else                      v = *(const float4*)(x + maxf - 4);
            *(float4*)(sA + f) = v;
        }
    }
    for (int f = tid * 4; f < IN_DIM * 256; f += 1024)
        *(float4*)(sB + f) = *(const float4*)(Bt + f);
    __syncthreads();

    int tn = tid & 7, tc = tid >> 3;
    float acc[8][8];
    #pragma unroll
    for (int i = 0; i < 8; ++i)
        #pragma unroll
        for (int c = 0; c < 8; ++c) acc[i][c] = 0.0f;

    #pragma unroll
    for (int kt = 0; kt < 5; ++kt) {   // K = 20 in steps of 4
        float4 a[8], b0[4], b1[4];
        #pragma unroll
        for (int i = 0; i < 8; ++i)
            a[i] = *(const float4*)(sA + (tn + 8 * i) * IN_DIM + kt * 4);
        #pragma unroll
        for (int j = 0; j < 4; ++j) {
            b0[j] = *(const float4*)(sB + (kt * 4 + j) * 256 + tc * 8);
            b1[j] = *(const float4*)(sB + (kt * 4 + j) * 256 + tc * 8 + 4);
        }
        #pragma unroll
        for (int i = 0; i < 8; ++i) {
            const float* ap = (const float*)&a[i];
            #pragma unroll
            for (int j = 0; j < 4; ++j) {
                float av = ap[j];
                const float* p0 = (const float*)&b0[j];
                const float* p1 = (const float*)&b1[j];
                #pragma unroll
                for (int c = 0; c < 4; ++c) {
                    acc[i][c]     += av * p0[c];
                    acc[i][c + 4] += av * p1[c];
                }
            }
        }
    }
    // epilogue
    int c0 = tc * 8;
    float4 bias0, bias1;
    if (c0 < 128) {
        bias0 = *(const float4*)(bl + c0);
        bias1 = *(const float4*)(bl + c0 + 4);
    } else {
        bias0 = *(const float4*)(br + c0 - 128);
        bias1 = *(const float4*)(br + c0 - 124);
    }
    const float* q0 = (const float*)&bias0;
    const float* q1 = (const float*)&bias1;
    #pragma unroll
    for (int i = 0; i < 8; ++i) {
        int n = nb + tn + 8 * i;
        if (n >= NNODES) continue;
        float4 o0, o1;
        float* w0 = (float*)&o0; float* w1 = (float*)&o1;
        #pragma unroll
        for (int c = 0; c < 4; ++c) { w0[c] = acc[i][c] + q0[c]; w1[c] = acc[i][c + 4] + q1[c]; }
        if (c0 < 128) {
            *(float4*)(xl + (size_t)n * HC1 + c0)     = o0;
            *(float4*)(xl + (size_t)n * HC1 + c0 + 4) = o1;
        } else {
            *(float4*)(xr + (size_t)n * HC1 + c0 - 128) = o0;
            *(float4*)(xr + (size_t)n * HC1 + c0 - 124) = o1;
        }
    }
}

// ================= layer-2 GEMM: [N x 128] @ Bt2 -> xl2|xr2 [N x 64] each ====
// block: 64 nodes x 128 cols; thread: 8 nodes (tn+8i) x 4 cols (tc*4..+3)
// sA row stride 132 (132%32==4 -> conflict-free b128 frag reads)
__global__ __launch_bounds__(256) void k_gemm2(
        const float* __restrict__ h1, const float* __restrict__ Bt,
        const float* __restrict__ bl, const float* __restrict__ br,
        float* __restrict__ xl2, float* __restrict__ xr2) {
    __shared__ float sA[64 * 132];   // 33792 B
    __shared__ float sB[32 * 128];   // 16384 B (k-chunk of 32)
    int nb = blockIdx.x * 64;
    int tid = threadIdx.x;
    // stage A: 64 x 128, reshaped to stride 132
    for (int f = tid * 4; f < 64 * HC1; f += 1024) {
        int node = f >> 7, k = f & 127;
        int gn = nb + node; if (gn >= NNODES) gn = NNODES - 1;
        float4 v = *(const float4*)(h1 + (size_t)gn * HC1 + k);
        *(float4*)(sA + node * 132 + k) = v;
    }
    int tn = tid & 7, tc = tid >> 3;
    float acc[8][4];
    #pragma unroll
    for (int i = 0; i < 8; ++i)
        #pragma unroll
        for (int c = 0; c < 4; ++c) acc[i][c] = 0.0f;

    for (int kc = 0; kc < 4; ++kc) {   // 4 chunks of 32 k
        __syncthreads();
        for (int f = tid * 4; f < 32 * 128; f += 1024)
            *(float4*)(sB + f) = *(const float4*)(Bt + kc * 4096 + f);
        __syncthreads();
        #pragma unroll
        for (int ks = 0; ks < 8; ++ks) {   // 8 k-steps of 4
            int k0 = kc * 32 + ks * 4;
            float4 a[8], b[4];
            #pragma unroll
            for (int i = 0; i < 8; ++i)
                a[i] = *(const float4*)(sA + (tn + 8 * i) * 132 + k0);
            #pragma unroll
            for (int j = 0; j < 4; ++j)
                b[j] = *(const float4*)(sB + (ks * 4 + j) * 128 + tc * 4);
            #pragma unroll
            for (int i = 0; i < 8; ++i) {
                const float* ap = (const float*)&a[i];
                #pragma unroll
                for (int j = 0; j < 4; ++j) {
                    float av = ap[j];
                    const float* bp = (const float*)&b[j];
                    #pragma unroll
                    for (int c = 0; c < 4; ++c) acc[i][c] += av * bp[c];
                }
            }
        }
    }
    // epilogue
    int c0 = tc * 4;
    float4 bias;
    if (c0 < 64) bias = *(const float4*)(bl + c0);
    else         bias = *(const float4*)(br + c0 - 64);
    const float* q = (const float*)&bias;
    #pragma unroll
    for (int i = 0; i < 8; ++i) {
        int n = nb + tn + 8 * i;
        if (n >= NNODES) continue;
        float4 o; float* w = (float*)&o;
        #pragma unroll
        for (int c = 0; c < 4; ++c) w[c] = acc[i][c] + q[c];
        if (c0 < 64) *(float4*)(xl2 + (size_t)n * OUTC + c0)      = o;
        else         *(float4*)(xr2 + (size_t)n * OUTC + c0 - 64) = o;
    }
}

// ================= fused per-node edge kernels (online softmax) =================
__global__ void k_node1(const int* __restrict__ rowptr, const int* __restrict__ csrc,
                        const float* __restrict__ cea, const float* __restrict__ easum,
                        const float* __restrict__ xl, const float* __restrict__ xr,
                        const float* __restrict__ We, const float* __restrict__ att,
                        const float* __restrict__ bias, float* __restrict__ h1) {
    int n = blockIdx.x * 4 + (threadIdx.x >> 6);
    int lane = threadIdx.x & 63;
    if (n >= NNODES) return;
    int c = lane * 2;
    float2 xrd = *(const float2*)(xr + (size_t)n * HC1 + c);
    float2 we  = *(const float2*)(We + c);
    float2 at  = *(const float2*)(att + c);
    float m = -1e30f, s = 0.f, acc0 = 0.f, acc1 = 0.f;
    int start = rowptr[n], end = rowptr[n + 1];
    float amean = easum[0] * (1.0f / (float)NEDGES);
    for (int base = start; base < end + 1; base += 64) {
        int rem = end + 1 - base;
        int cnt_ = rem < 64 ? rem : 64;
        int idx = base + lane;
        int sl = 0; float al = 0.f;
        if (lane < cnt_) {
            if (idx < end) { sl = csrc[idx]; al = cea[idx]; }
            else           { sl = n;         al = amean;    }
        }
        for (int j = 0; j < cnt_; ++j) {
            int   src = __shfl(sl, j, 64);
            float a   = __shfl(al, j, 64);
            float2 xs = *(const float2*)(xl + (size_t)src * HC1 + c);
            float e0 = lrelu(xs.x + xrd.x + a * we.x);
            float e1 = lrelu(xs.y + xrd.y + a * we.y);
            float p = e0 * at.x + e1 * at.y;
            p += __shfl_xor(p, 1, 64);
            p += __shfl_xor(p, 2, 64);
            p += __shfl_xor(p, 4, 64);
            p += __shfl_xor(p, 8, 64);
            float mn = fmaxf(m, p);
            float sc = __expf(m - mn);
            float pe = __expf(p - mn);
            s    = s * sc + pe;
            acc0 = acc0 * sc + pe * xs.x;
            acc1 = acc1 * sc + pe * xs.y;
            m = mn;
        }
    }
    float inv = 1.0f / s;
    float v0 = acc0 * inv + bias[c];
    float v1 = acc1 * inv + bias[c + 1];
    v0 = v0 > 0.f ? v0 : expm1f(v0);
    v1 = v1 > 0.f ? v1 : expm1f(v1);
    *(float2*)(h1 + (size_t)n * HC1 + c) = make_float2(v0, v1);
}

__global__ void k_node2(const int* __restrict__ rowptr, const int* __restrict__ csrc,
                        const float* __restrict__ cea, const float* __restrict__ easum,
                        const float* __restrict__ xl2, const float* __restrict__ xr2,
                        const float* __restrict__ We, const float* __restrict__ att,
                        const float* __restrict__ bias, float* __restrict__ out) {
    int n = blockIdx.x * 4 + (threadIdx.x >> 6);
    int lane = threadIdx.x & 63;
    if (n >= NNODES) return;
    float xrd = xr2[(size_t)n * OUTC + lane];
    float we  = We[lane];
    float at  = att[lane];
    float m = -1e30f, s = 0.f, acc = 0.f;
    int start = rowptr[n], end = rowptr[n + 1];
    float amean = easum[0] * (1.0f / (float)NEDGES);
    for (int base = start; base < end + 1; base += 64) {
        int rem = end + 1 - base;
        int cnt_ = rem < 64 ? rem : 64;
        int idx = base + lane;
        int sl = 0; float al = 0.f;
        if (lane < cnt_) {
            if (idx < end) { sl = csrc[idx]; al = cea[idx]; }
            else           { sl = n;         al = amean;    }
        }
        for (int j = 0; j < cnt_; ++j) {
            int   src = __shfl(sl, j, 64);
            float a   = __shfl(al, j, 64);
            float xs = xl2[(size_t)src * OUTC + lane];
            float p = lrelu(xs + xrd + a * we) * at;
            p += __shfl_xor(p, 1, 64);
            p += __shfl_xor(p, 2, 64);
            p += __shfl_xor(p, 4, 64);
            p += __shfl_xor(p, 8, 64);
            p += __shfl_xor(p, 16, 64);
            p += __shfl_xor(p, 32, 64);
            float mn = fmaxf(m, p);
            float sc = __expf(m - mn);
            float pe = __expf(p - mn);
            s   = s * sc + pe;
            acc = acc * sc + pe * xs;
            m = mn;
        }
    }
    out[(size_t)n * OUTC + lane] = acc / s + bias[lane];
}

extern "C" void kernel_launch(void* const* d_in, const int* in_sizes, int n_in,
                              void* d_out, int out_size, void* d_ws, size_t ws_size,
                              hipStream_t stream) {
    (void)in_sizes; (void)n_in; (void)out_size; (void)ws_size;
    const float* x    = (const float*)d_in[0];
    const int*   ei   = (const int*)d_in[1];
    const float* ea   = (const float*)d_in[2];
    const float* Wl1  = (const float*)d_in[3];
    const float* bl1  = (const float*)d_in[4];
    const float* Wr1  = (const float*)d_in[5];
    const float* br1  = (const float*)d_in[6];
    const float* We1  = (const float*)d_in[7];
    const float* att1 = (const float*)d_in[8];
    const float* b1   = (const float*)d_in[9];
    const float* Wl2  = (const float*)d_in[10];
    const float* bl2  = (const float*)d_in[11];
    const float* Wr2  = (const float*)d_in[12];
    const float* br2  = (const float*)d_in[13];
    const float* We2  = (const float*)d_in[14];
    const float* att2 = (const float*)d_in[15];
    const float* b2   = (const float*)d_in[16];
    float* out = (float*)d_out;

    // ---- workspace layout ----
    float* ws = (float*)d_ws;
    size_t off = 0;
    float* xl     = ws + off; off += (size_t)NNODES * HC1;
    float* xr     = ws + off; off += (size_t)NNODES * HC1;
    float* h1     = ws + off; off += (size_t)NNODES * HC1;
    int*   csrc   = (int*)(ws + off);   off += NEDGES;
    float* cea    = ws + off;           off += NEDGES;
    int*   cnt    = (int*)(ws + off);   off += NNODES;
    int*   rowptr = (int*)(ws + off);   off += NNODES + 1;
    int*   fill   = (int*)(ws + off);   off += NNODES;
    int*   csums  = (int*)(ws + off);   off += 512;
    float* easum  = ws + off;           off += 1;
    float* Bt1    = ws + off;           off += 20 * 256;
    float* Bt2    = ws + off;           off += 128 * 128;
    float* xl2 = xl;
    float* xr2 = xr;

    hipMemsetAsync(easum, 0, sizeof(float), stream);
    hipMemsetAsync(cnt,  0, (size_t)NNODES * 4, stream);
    hipMemsetAsync(fill, 0, (size_t)NNODES * 4, stream);

    // ---- CSR build + weight prep ----
    k_sum<<<256, 256, 0, stream>>>(ea, NEDGES, easum);
    k_hist<<<(NEDGES + 255) / 256, 256, 0, stream>>>(ei, cnt);
    k_prepB1<<<(20 * 256 + 255) / 256, 256, 0, stream>>>(Wl1, Wr1, Bt1);
    k_prepB2<<<(128 * 128 + 255) / 256, 256, 0, stream>>>(Wl2, Wr2, Bt2);
    k_scan_chunk<<<NCHUNK, 256, 0, stream>>>(cnt, rowptr, csums);
    k_scan_tops<<<1, 512, 0, stream>>>(csums);
    k_scan_add<<<NCHUNK, 256, 0, stream>>>(rowptr, csums);
    k_scatter<<<(NEDGES + 255) / 256, 256, 0, stream>>>(ei, ea, rowptr, fill, csrc, cea);

    // ---- layer 1 ----
    k_gemm1<<<NBLK, 256, 0, stream>>>(x, Bt1, bl1, br1, xl, xr);
    k_node1<<<(NNODES + 3) / 4, 256, 0, stream>>>(rowptr, csrc, cea, easum,
                                                  xl, xr, We1, att1, b1, h1);

    // ---- layer 2 ----
    k_gemm2<<<NBLK, 256, 0, stream>>>(h1, Bt2, bl2, br2, xl2, xr2);
    k_node2<<<(NNODES + 3) / 4, 256, 0, stream>>>(rowptr, csrc, cea, easum,
                                                  xl2, xr2, We2, att2, b2, out);
}

// Round 4
// 616.498 us; speedup vs baseline: 30.4586x; 1.1940x over previous
//
#include <hip/hip_runtime.h>
#include <cstdint>
#include <cstddef>

#define NNODES 100000
#define NEDGES 1600000
#define IN_DIM 20
#define HID    32
#define HEADS  4
#define HC1    128
#define OUTC   64
#define NEG    0.2f
#define NCHUNK ((NNODES + 255) / 256)   // 391
#define NBLK   ((NNODES + 63) / 64)     // 1563

__device__ __forceinline__ float lrelu(float v) { return v >= 0.0f ? v : NEG * v; }

// ---- sum of edge_attr (for self-loop fill value) ----
__global__ void k_sum(const float* __restrict__ ea, int n, float* __restrict__ out) {
    float s = 0.0f;
    for (int i = blockIdx.x * blockDim.x + threadIdx.x; i < n; i += gridDim.x * blockDim.x)
        s += ea[i];
    #pragma unroll
    for (int off = 32; off > 0; off >>= 1) s += __shfl_down(s, off, 64);
    __shared__ float ls[4];
    int lane = threadIdx.x & 63, wid = threadIdx.x >> 6;
    if (lane == 0) ls[wid] = s;
    __syncthreads();
    if (threadIdx.x == 0) {
        float t = ls[0] + ls[1] + ls[2] + ls[3];
        atomicAdd(out, t);
    }
}

// ================= CSR build (by destination) =================
__global__ void k_hist(const int* __restrict__ ei, int* __restrict__ cnt) {
    int e = blockIdx.x * blockDim.x + threadIdx.x;
    if (e < NEDGES) atomicAdd(&cnt[ei[NEDGES + e]], 1);
}

__global__ void k_scan_chunk(const int* __restrict__ cnt, int* __restrict__ rowptr,
                             int* __restrict__ csums) {
    __shared__ int s[256];
    int i = blockIdx.x * 256 + threadIdx.x;
    int v = (i < NNODES) ? cnt[i] : 0;
    s[threadIdx.x] = v;
    __syncthreads();
    for (int off = 1; off < 256; off <<= 1) {
        int t = (threadIdx.x >= off) ? s[threadIdx.x - off] : 0;
        __syncthreads();
        s[threadIdx.x] += t;
        __syncthreads();
    }
    if (i < NNODES) rowptr[i] = s[threadIdx.x] - v;
    if (threadIdx.x == 255) csums[blockIdx.x] = s[255];
}

__global__ void k_scan_tops(int* __restrict__ csums) {
    __shared__ int s[512];
    int v = (threadIdx.x < NCHUNK) ? csums[threadIdx.x] : 0;
    s[threadIdx.x] = v;
    __syncthreads();
    for (int off = 1; off < 512; off <<= 1) {
        int t = (threadIdx.x >= off) ? s[threadIdx.x - off] : 0;
        __syncthreads();
        s[threadIdx.x] += t;
        __syncthreads();
    }
    if (threadIdx.x < NCHUNK) csums[threadIdx.x] = s[threadIdx.x] - v;
}

__global__ void k_scan_add(int* __restrict__ rowptr, const int* __restrict__ csums) {
    int i = blockIdx.x * 256 + threadIdx.x;
    if (i < NNODES) rowptr[i] += csums[blockIdx.x];
    if (i == 0) rowptr[NNODES] = NEDGES;
}

__global__ void k_scatter(const int* __restrict__ ei, const float* __restrict__ ea,
                          const int* __restrict__ rowptr, int* __restrict__ fill,
                          int* __restrict__ csrc, float* __restrict__ cea) {
    int e = blockIdx.x * blockDim.x + threadIdx.x;
    if (e >= NEDGES) return;
    int dst = ei[NEDGES + e];
    int pos = rowptr[dst] + atomicAdd(&fill[dst], 1);
    csrc[pos] = ei[e];
    cea[pos] = ea[e];
}

// ================= weight prep =================
__global__ void k_prepB1(const float* __restrict__ Wl, const float* __restrict__ Wr,
                         float* __restrict__ Bt) {
    int idx = blockIdx.x * 256 + threadIdx.x;
    if (idx >= 20 * 256) return;
    int k = idx >> 8, c = idx & 255;
    Bt[idx] = (c < 128) ? Wl[c * IN_DIM + k] : Wr[(c - 128) * IN_DIM + k];
}
__global__ void k_prepB2(const float* __restrict__ Wl, const float* __restrict__ Wr,
                         float* __restrict__ Bt) {
    int idx = blockIdx.x * 256 + threadIdx.x;
    if (idx >= 128 * 128) return;
    int k = idx >> 7, c = idx & 127;
    Bt[idx] = (c < 64) ? Wl[c * HC1 + k] : Wr[(c - 64) * HC1 + k];
}

// ================= layer-1 GEMM =================
__global__ __launch_bounds__(256) void k_gemm1(
        const float* __restrict__ x, const float* __restrict__ Bt,
        const float* __restrict__ bl, const float* __restrict__ br,
        float* __restrict__ xl, float* __restrict__ xr) {
    __shared__ float sA[64 * IN_DIM];
    __shared__ float sB[IN_DIM * 256];
    int nb = blockIdx.x * 64;
    int tid = threadIdx.x;
    {
        size_t base = (size_t)nb * IN_DIM;
        size_t maxf = (size_t)NNODES * IN_DIM;
        for (int f = tid * 4; f < 64 * IN_DIM; f += 1024) {
            float4 v;
            if (base + f + 4 <= maxf) v = *(const float4*)(x + base + f);
            else                      v = *(const float4*)(x + maxf - 4);
            *(float4*)(sA + f) = v;
        }
    }
    for (int f = tid * 4; f < IN_DIM * 256; f += 1024)
        *(float4*)(sB + f) = *(const float4*)(Bt + f);
    __syncthreads();

    int tn = tid & 7, tc = tid >> 3;
    float acc[8][8];
    #pragma unroll
    for (int i = 0; i < 8; ++i)
        #pragma unroll
        for (int c = 0; c < 8; ++c) acc[i][c] = 0.0f;

    #pragma unroll
    for (int kt = 0; kt < 5; ++kt) {
        float4 a[8], b0[4], b1[4];
        #pragma unroll
        for (int i = 0; i < 8; ++i)
            a[i] = *(const float4*)(sA + (tn + 8 * i) * IN_DIM + kt * 4);
        #pragma unroll
        for (int j = 0; j < 4; ++j) {
            b0[j] = *(const float4*)(sB + (kt * 4 + j) * 256 + tc * 8);
            b1[j] = *(const float4*)(sB + (kt * 4 + j) * 256 + tc * 8 + 4);
        }
        #pragma unroll
        for (int i = 0; i < 8; ++i) {
            const float* ap = (const float*)&a[i];
            #pragma unroll
            for (int j = 0; j < 4; ++j) {
                float av = ap[j];
                const float* p0 = (const float*)&b0[j];
                const float* p1 = (const float*)&b1[j];
                #pragma unroll
                for (int c = 0; c < 4; ++c) {
                    acc[i][c]     += av * p0[c];
                    acc[i][c + 4] += av * p1[c];
                }
            }
        }
    }
    int c0 = tc * 8;
    float4 bias0, bias1;
    if (c0 < 128) {
        bias0 = *(const float4*)(bl + c0);
        bias1 = *(const float4*)(bl + c0 + 4);
    } else {
        bias0 = *(const float4*)(br + c0 - 128);
        bias1 = *(const float4*)(br + c0 - 124);
    }
    const float* q0 = (const float*)&bias0;
    const float* q1 = (const float*)&bias1;
    #pragma unroll
    for (int i = 0; i < 8; ++i) {
        int n = nb + tn + 8 * i;
        if (n >= NNODES) continue;
        float4 o0, o1;
        float* w0 = (float*)&o0; float* w1 = (float*)&o1;
        #pragma unroll
        for (int c = 0; c < 4; ++c) { w0[c] = acc[i][c] + q0[c]; w1[c] = acc[i][c + 4] + q1[c]; }
        if (c0 < 128) {
            *(float4*)(xl + (size_t)n * HC1 + c0)     = o0;
            *(float4*)(xl + (size_t)n * HC1 + c0 + 4) = o1;
        } else {
            *(float4*)(xr + (size_t)n * HC1 + c0 - 128) = o0;
            *(float4*)(xr + (size_t)n * HC1 + c0 - 124) = o1;
        }
    }
}

// ================= layer-2 GEMM =================
__global__ __launch_bounds__(256) void k_gemm2(
        const float* __restrict__ h1, const float* __restrict__ Bt,
        const float* __restrict__ bl, const float* __restrict__ br,
        float* __restrict__ xl2, float* __restrict__ xr2) {
    __shared__ float sA[64 * 132];
    __shared__ float sB[32 * 128];
    int nb = blockIdx.x * 64;
    int tid = threadIdx.x;
    for (int f = tid * 4; f < 64 * HC1; f += 1024) {
        int node = f >> 7, k = f & 127;
        int gn = nb + node; if (gn >= NNODES) gn = NNODES - 1;
        float4 v = *(const float4*)(h1 + (size_t)gn * HC1 + k);
        *(float4*)(sA + node * 132 + k) = v;
    }
    int tn = tid & 7, tc = tid >> 3;
    float acc[8][4];
    #pragma unroll
    for (int i = 0; i < 8; ++i)
        #pragma unroll
        for (int c = 0; c < 4; ++c) acc[i][c] = 0.0f;

    for (int kc = 0; kc < 4; ++kc) {
        __syncthreads();
        for (int f = tid * 4; f < 32 * 128; f += 1024)
            *(float4*)(sB + f) = *(const float4*)(Bt + kc * 4096 + f);
        __syncthreads();
        #pragma unroll
        for (int ks = 0; ks < 8; ++ks) {
            int k0 = kc * 32 + ks * 4;
            float4 a[8], b[4];
            #pragma unroll
            for (int i = 0; i < 8; ++i)
                a[i] = *(const float4*)(sA + (tn + 8 * i) * 132 + k0);
            #pragma unroll
            for (int j = 0; j < 4; ++j)
                b[j] = *(const float4*)(sB + (ks * 4 + j) * 128 + tc * 4);
            #pragma unroll
            for (int i = 0; i < 8; ++i) {
                const float* ap = (const float*)&a[i];
                #pragma unroll
                for (int j = 0; j < 4; ++j) {
                    float av = ap[j];
                    const float* bp = (const float*)&b[j];
                    #pragma unroll
                    for (int c = 0; c < 4; ++c) acc[i][c] += av * bp[c];
                }
            }
        }
    }
    int c0 = tc * 4;
    float4 bias;
    if (c0 < 64) bias = *(const float4*)(bl + c0);
    else         bias = *(const float4*)(br + c0 - 64);
    const float* q = (const float*)&bias;
    #pragma unroll
    for (int i = 0; i < 8; ++i) {
        int n = nb + tn + 8 * i;
        if (n >= NNODES) continue;
        float4 o; float* w = (float*)&o;
        #pragma unroll
        for (int c = 0; c < 4; ++c) w[c] = acc[i][c] + q[c];
        if (c0 < 64) *(float4*)(xl2 + (size_t)n * OUTC + c0)      = o;
        else         *(float4*)(xr2 + (size_t)n * OUTC + c0 - 64) = o;
    }
}

// ================= fused per-node edge kernels (multi-edge-parallel online softmax) ====
// layer 1: 1 wave/node, 4 edge-groups x 16 lanes; lane holds 8 channels (head = q>>2)
__global__ __launch_bounds__(256) void k_node1(
        const int* __restrict__ rowptr, const int* __restrict__ csrc,
        const float* __restrict__ cea, const float* __restrict__ easum,
        const float* __restrict__ xl, const float* __restrict__ xr,
        const float* __restrict__ We, const float* __restrict__ att,
        const float* __restrict__ bias, float* __restrict__ h1) {
    int n = blockIdx.x * 4 + (threadIdx.x >> 6);
    if (n >= NNODES) return;
    int lane = threadIdx.x & 63;
    int g = lane >> 4;        // edge slot 0..3
    int q = lane & 15;        // channel oct; channels 8q..8q+7 (all in head q>>2)
    int c = q * 8;
    const float4* xrp = (const float4*)(xr + (size_t)n * HC1 + c);
    float4 xr0 = xrp[0], xr1 = xrp[1];
    float4 we0 = *(const float4*)(We + c),  we1 = *(const float4*)(We + c + 4);
    float4 at0 = *(const float4*)(att + c), at1 = *(const float4*)(att + c + 4);
    float m = -1e30f, s = 0.0f;
    float4 a0 = make_float4(0.f, 0.f, 0.f, 0.f), a1 = a0;
    int start = rowptr[n], end = rowptr[n + 1];
    int total = end + 1 - start;                 // + self edge at idx==end
    float amean = easum[0] * (1.0f / (float)NEDGES);
    for (int base = 0; base < total; base += 4) {
        int idx = start + base + g;
        bool valid = (base + g) < total;
        int src = n; float a = amean;
        if (idx < end) { src = csrc[idx]; a = cea[idx]; }
        const float4* xsp = (const float4*)(xl + (size_t)src * HC1 + c);
        float4 xs0 = xsp[0], xs1 = xsp[1];
        float p = lrelu(xs0.x + xr0.x + a * we0.x) * at0.x
                + lrelu(xs0.y + xr0.y + a * we0.y) * at0.y
                + lrelu(xs0.z + xr0.z + a * we0.z) * at0.z
                + lrelu(xs0.w + xr0.w + a * we0.w) * at0.w
                + lrelu(xs1.x + xr1.x + a * we1.x) * at1.x
                + lrelu(xs1.y + xr1.y + a * we1.y) * at1.y
                + lrelu(xs1.z + xr1.z + a * we1.z) * at1.z
                + lrelu(xs1.w + xr1.w + a * we1.w) * at1.w;
        p += __shfl_xor(p, 1, 64);
        p += __shfl_xor(p, 2, 64);               // head logit over its 4-lane quad
        if (valid) {
            float mn = fmaxf(m, p);
            float sc = __expf(m - mn);
            float pe = __expf(p - mn);
            s = s * sc + pe;
            a0.x = a0.x * sc + pe * xs0.x;  a0.y = a0.y * sc + pe * xs0.y;
            a0.z = a0.z * sc + pe * xs0.z;  a0.w = a0.w * sc + pe * xs0.w;
            a1.x = a1.x * sc + pe * xs1.x;  a1.y = a1.y * sc + pe * xs1.y;
            a1.z = a1.z * sc + pe * xs1.z;  a1.w = a1.w * sc + pe * xs1.w;
            m = mn;
        }
    }
    // merge the 4 groups (lane xor 16, 32), rescaling to the joint max
    #pragma unroll
    for (int off = 16; off <= 32; off <<= 1) {
        float m2 = __shfl_xor(m, off, 64);
        float s2 = __shfl_xor(s, off, 64);
        float4 b0, b1;
        b0.x = __shfl_xor(a0.x, off, 64); b0.y = __shfl_xor(a0.y, off, 64);
        b0.z = __shfl_xor(a0.z, off, 64); b0.w = __shfl_xor(a0.w, off, 64);
        b1.x = __shfl_xor(a1.x, off, 64); b1.y = __shfl_xor(a1.y, off, 64);
        b1.z = __shfl_xor(a1.z, off, 64); b1.w = __shfl_xor(a1.w, off, 64);
        float mn = fmaxf(m, m2);
        float sc = __expf(m - mn), sc2 = __expf(m2 - mn);
        s = s * sc + s2 * sc2;
        a0.x = a0.x * sc + b0.x * sc2;  a0.y = a0.y * sc + b0.y * sc2;
        a0.z = a0.z * sc + b0.z * sc2;  a0.w = a0.w * sc + b0.w * sc2;
        a1.x = a1.x * sc + b1.x * sc2;  a1.y = a1.y * sc + b1.y * sc2;
        a1.z = a1.z * sc + b1.z * sc2;  a1.w = a1.w * sc + b1.w * sc2;
        m = mn;
    }
    if (g == 0) {
        float inv = 1.0f / s;
        float4 bi0 = *(const float4*)(bias + c), bi1 = *(const float4*)(bias + c + 4);
        float4 o0, o1;
        o0.x = a0.x * inv + bi0.x;  o0.y = a0.y * inv + bi0.y;
        o0.z = a0.z * inv + bi0.z;  o0.w = a0.w * inv + bi0.w;
        o1.x = a1.x * inv + bi1.x;  o1.y = a1.y * inv + bi1.y;
        o1.z = a1.z * inv + bi1.z;  o1.w = a1.w * inv + bi1.w;
        o0.x = o0.x > 0.f ? o0.x : expm1f(o0.x);  o0.y = o0.y > 0.f ? o0.y : expm1f(o0.y);
        o0.z = o0.z > 0.f ? o0.z : expm1f(o0.z);  o0.w = o0.w > 0.f ? o0.w : expm1f(o0.w);
        o1.x = o1.x > 0.f ? o1.x : expm1f(o1.x);  o1.y = o1.y > 0.f ? o1.y : expm1f(o1.y);
        o1.z = o1.z > 0.f ? o1.z : expm1f(o1.z);  o1.w = o1.w > 0.f ? o1.w : expm1f(o1.w);
        float4* op = (float4*)(h1 + (size_t)n * HC1 + c);
        op[0] = o0; op[1] = o1;
    }
}

// layer 2: 1 wave/node, 8 edge-groups x 8 lanes; lane holds 8 channels (single head)
__global__ __launch_bounds__(256) void k_node2(
        const int* __restrict__ rowptr, const int* __restrict__ csrc,
        const float* __restrict__ cea, const float* __restrict__ easum,
        const float* __restrict__ xl2, const float* __restrict__ xr2,
        const float* __restrict__ We, const float* __restrict__ att,
        const float* __restrict__ bias, float* __restrict__ out) {
    int n = blockIdx.x * 4 + (threadIdx.x >> 6);
    if (n >= NNODES) return;
    int lane = threadIdx.x & 63;
    int g = lane >> 3;        // edge slot 0..7
    int q = lane & 7;         // channel oct; channels 8q..8q+7
    int c = q * 8;
    const float4* xrp = (const float4*)(xr2 + (size_t)n * OUTC + c);
    float4 xr0 = xrp[0], xr1 = xrp[1];
    float4 we0 = *(const float4*)(We + c),  we1 = *(const float4*)(We + c + 4);
    float4 at0 = *(const float4*)(att + c), at1 = *(const float4*)(att + c + 4);
    float m = -1e30f, s = 0.0f;
    float4 a0 = make_float4(0.f, 0.f, 0.f, 0.f), a1 = a0;
    int start = rowptr[n], end = rowptr[n + 1];
    int total = end + 1 - start;
    float amean = easum[0] * (1.0f / (float)NEDGES);
    for (int base = 0; base < total; base += 8) {
        int idx = start + base + g;
        bool valid = (base + g) < total;
        int src = n; float a = amean;
        if (idx < end) { src = csrc[idx]; a = cea[idx]; }
        const float4* xsp = (const float4*)(xl2 + (size_t)src * OUTC + c);
        float4 xs0 = xsp[0], xs1 = xsp[1];
        float p = lrelu(xs0.x + xr0.x + a * we0.x) * at0.x
                + lrelu(xs0.y + xr0.y + a * we0.y) * at0.y
                + lrelu(xs0.z + xr0.z + a * we0.z) * at0.z
                + lrelu(xs0.w + xr0.w + a * we0.w) * at0.w
                + lrelu(xs1.x + xr1.x + a * we1.x) * at1.x
                + lrelu(xs1.y + xr1.y + a * we1.y) * at1.y
                + lrelu(xs1.z + xr1.z + a * we1.z) * at1.z
                + lrelu(xs1.w + xr1.w + a * we1.w) * at1.w;
        p += __shfl_xor(p, 1, 64);
        p += __shfl_xor(p, 2, 64);
        p += __shfl_xor(p, 4, 64);               // edge logit over the 8-lane group
        if (valid) {
            float mn = fmaxf(m, p);
            float sc = __expf(m - mn);
            float pe = __expf(p - mn);
            s = s * sc + pe;
            a0.x = a0.x * sc + pe * xs0.x;  a0.y = a0.y * sc + pe * xs0.y;
            a0.z = a0.z * sc + pe * xs0.z;  a0.w = a0.w * sc + pe * xs0.w;
            a1.x = a1.x * sc + pe * xs1.x;  a1.y = a1.y * sc + pe * xs1.y;
            a1.z = a1.z * sc + pe * xs1.z;  a1.w = a1.w * sc + pe * xs1.w;
            m = mn;
        }
    }
    #pragma unroll
    for (int off = 8; off <= 32; off <<= 1) {
        float m2 = __shfl_xor(m, off, 64);
        float s2 = __shfl_xor(s, off, 64);
        float4 b0, b1;
        b0.x = __shfl_xor(a0.x, off, 64); b0.y = __shfl_xor(a0.y, off, 64);
        b0.z = __shfl_xor(a0.z, off, 64); b0.w = __shfl_xor(a0.w, off, 64);
        b1.x = __shfl_xor(a1.x, off, 64); b1.y = __shfl_xor(a1.y, off, 64);
        b1.z = __shfl_xor(a1.z, off, 64); b1.w = __shfl_xor(a1.w, off, 64);
        float mn = fmaxf(m, m2);
        float sc = __expf(m - mn), sc2 = __expf(m2 - mn);
        s = s * sc + s2 * sc2;
        a0.x = a0.x * sc + b0.x * sc2;  a0.y = a0.y * sc + b0.y * sc2;
        a0.z = a0.z * sc + b0.z * sc2;  a0.w = a0.w * sc + b0.w * sc2;
        a1.x = a1.x * sc + b1.x * sc2;  a1.y = a1.y * sc + b1.y * sc2;
        a1.z = a1.z * sc + b1.z * sc2;  a1.w = a1.w * sc + b1.w * sc2;
        m = mn;
    }
    if (g == 0) {
        float inv = 1.0f / s;
        float4 bi0 = *(const float4*)(bias + c), bi1 = *(const float4*)(bias + c + 4);
        float4 o0, o1;
        o0.x = a0.x * inv + bi0.x;  o0.y = a0.y * inv + bi0.y;
        o0.z = a0.z * inv + bi0.z;  o0.w = a0.w * inv + bi0.w;
        o1.x = a1.x * inv + bi1.x;  o1.y = a1.y * inv + bi1.y;
        o1.z = a1.z * inv + bi1.z;  o1.w = a1.w * inv + bi1.w;
        float4* op = (float4*)(out + (size_t)n * OUTC + c);
        op[0] = o0; op[1] = o1;
    }
}

extern "C" void kernel_launch(void* const* d_in, const int* in_sizes, int n_in,
                              void* d_out, int out_size, void* d_ws, size_t ws_size,
                              hipStream_t stream) {
    (void)in_sizes; (void)n_in; (void)out_size; (void)ws_size;
    const float* x    = (const float*)d_in[0];
    const int*   ei   = (const int*)d_in[1];
    const float* ea   = (const float*)d_in[2];
    const float* Wl1  = (const float*)d_in[3];
    const float* bl1  = (const float*)d_in[4];
    const float* Wr1  = (const float*)d_in[5];
    const float* br1  = (const float*)d_in[6];
    const float* We1  = (const float*)d_in[7];
    const float* att1 = (const float*)d_in[8];
    const float* b1   = (const float*)d_in[9];
    const float* Wl2  = (const float*)d_in[10];
    const float* bl2  = (const float*)d_in[11];
    const float* Wr2  = (const float*)d_in[12];
    const float* br2  = (const float*)d_in[13];
    const float* We2  = (const float*)d_in[14];
    const float* att2 = (const float*)d_in[15];
    const float* b2   = (const float*)d_in[16];
    float* out = (float*)d_out;

    float* ws = (float*)d_ws;
    size_t off = 0;
    float* xl     = ws + off; off += (size_t)NNODES * HC1;
    float* xr     = ws + off; off += (size_t)NNODES * HC1;
    float* h1     = ws + off; off += (size_t)NNODES * HC1;
    int*   csrc   = (int*)(ws + off);   off += NEDGES;
    float* cea    = ws + off;           off += NEDGES;
    int*   cnt    = (int*)(ws + off);   off += NNODES;
    int*   rowptr = (int*)(ws + off);   off += NNODES + 1;
    int*   fill   = (int*)(ws + off);   off += NNODES;
    int*   csums  = (int*)(ws + off);   off += 512;
    float* easum  = ws + off;           off += 1;
    float* Bt1    = ws + off;           off += 20 * 256;
    float* Bt2    = ws + off;           off += 128 * 128;
    float* xl2 = xl;
    float* xr2 = xr;

    hipMemsetAsync(easum, 0, sizeof(float), stream);
    hipMemsetAsync(cnt,  0, (size_t)NNODES * 4, stream);
    hipMemsetAsync(fill, 0, (size_t)NNODES * 4, stream);

    k_sum<<<256, 256, 0, stream>>>(ea, NEDGES, easum);
    k_hist<<<(NEDGES + 255) / 256, 256, 0, stream>>>(ei, cnt);
    k_prepB1<<<(20 * 256 + 255) / 256, 256, 0, stream>>>(Wl1, Wr1, Bt1);
    k_prepB2<<<(128 * 128 + 255) / 256, 256, 0, stream>>>(Wl2, Wr2, Bt2);
    k_scan_chunk<<<NCHUNK, 256, 0, stream>>>(cnt, rowptr, csums);
    k_scan_tops<<<1, 512, 0, stream>>>(csums);
    k_scan_add<<<NCHUNK, 256, 0, stream>>>(rowptr, csums);
    k_scatter<<<(NEDGES + 255) / 256, 256, 0, stream>>>(ei, ea, rowptr, fill, csrc, cea);

    k_gemm1<<<NBLK, 256, 0, stream>>>(x, Bt1, bl1, br1, xl, xr);
    k_node1<<<(NNODES + 3) / 4, 256, 0, stream>>>(rowptr, csrc, cea, easum,
                                                  xl, xr, We1, att1, b1, h1);

    k_gemm2<<<NBLK, 256, 0, stream>>>(h1, Bt2, bl2, br2, xl2, xr2);
    k_node2<<<(NNODES + 3) / 4, 256, 0, stream>>>(rowptr, csrc, cea, easum,
                                                  xl2, xr2, We2, att2, b2, out);
}

// Round 6
// 545.881 us; speedup vs baseline: 34.3988x; 1.1294x over previous
//
#include <hip/hip_runtime.h>
#include <cstdint>
#include <cstddef>

#define NNODES 100000
#define NEDGES 1600000
#define IN_DIM 20
#define HID    32
#define HEADS  4
#define HC1    128
#define OUTC   64
#define NEG    0.2f
#define NCHUNK ((NNODES + 255) / 256)   // 391
#define NBLK   ((NNODES + 63) / 64)     // 1563

__device__ __forceinline__ float lrelu(float v) { return v >= 0.0f ? v : NEG * v; }

// clang-native packed half: arithmetic lowers to v_pk_*_f16, no HIP half API needed
typedef _Float16 h2 __attribute__((ext_vector_type(2)));
union U4H { uint4 u; h2 h[4]; };
union U2H { uint2 u; h2 h[2]; };

// ---- sum of edge_attr (for self-loop fill value) ----
__global__ void k_sum(const float* __restrict__ ea, int n, float* __restrict__ out) {
    float s = 0.0f;
    for (int i = blockIdx.x * blockDim.x + threadIdx.x; i < n; i += gridDim.x * blockDim.x)
        s += ea[i];
    #pragma unroll
    for (int off = 32; off > 0; off >>= 1) s += __shfl_down(s, off, 64);
    __shared__ float ls[4];
    int lane = threadIdx.x & 63, wid = threadIdx.x >> 6;
    if (lane == 0) ls[wid] = s;
    __syncthreads();
    if (threadIdx.x == 0) {
        float t = ls[0] + ls[1] + ls[2] + ls[3];
        atomicAdd(out, t);
    }
}

// ================= CSR build (by destination) =================
__global__ void k_hist(const int* __restrict__ ei, int* __restrict__ cnt) {
    int e = blockIdx.x * blockDim.x + threadIdx.x;
    if (e < NEDGES) atomicAdd(&cnt[ei[NEDGES + e]], 1);
}

__global__ void k_scan_chunk(const int* __restrict__ cnt, int* __restrict__ rowptr,
                             int* __restrict__ csums) {
    __shared__ int s[256];
    int i = blockIdx.x * 256 + threadIdx.x;
    int v = (i < NNODES) ? cnt[i] : 0;
    s[threadIdx.x] = v;
    __syncthreads();
    for (int off = 1; off < 256; off <<= 1) {
        int t = (threadIdx.x >= off) ? s[threadIdx.x - off] : 0;
        __syncthreads();
        s[threadIdx.x] += t;
        __syncthreads();
    }
    if (i < NNODES) rowptr[i] = s[threadIdx.x] - v;
    if (threadIdx.x == 255) csums[blockIdx.x] = s[255];
}

__global__ void k_scan_tops(int* __restrict__ csums) {
    __shared__ int s[512];
    int v = (threadIdx.x < NCHUNK) ? csums[threadIdx.x] : 0;
    s[threadIdx.x] = v;
    __syncthreads();
    for (int off = 1; off < 512; off <<= 1) {
        int t = (threadIdx.x >= off) ? s[threadIdx.x - off] : 0;
        __syncthreads();
        s[threadIdx.x] += t;
        __syncthreads();
    }
    if (threadIdx.x < NCHUNK) csums[threadIdx.x] = s[threadIdx.x] - v;
}

__global__ void k_scan_add(int* __restrict__ rowptr, const int* __restrict__ csums) {
    int i = blockIdx.x * 256 + threadIdx.x;
    if (i < NNODES) rowptr[i] += csums[blockIdx.x];
    if (i == 0) rowptr[NNODES] = NEDGES;
}

__global__ void k_scatter(const int* __restrict__ ei, const float* __restrict__ ea,
                          const int* __restrict__ rowptr, int* __restrict__ fill,
                          int2* __restrict__ cedge) {
    int e = blockIdx.x * blockDim.x + threadIdx.x;
    if (e >= NEDGES) return;
    int dst = ei[NEDGES + e];
    int pos = rowptr[dst] + atomicAdd(&fill[dst], 1);
    cedge[pos] = make_int2(ei[e], __float_as_int(ea[e]));
}

// ================= weight prep =================
__global__ void k_prepB1(const float* __restrict__ Wl, const float* __restrict__ Wr,
                         float* __restrict__ Bt) {
    int idx = blockIdx.x * 256 + threadIdx.x;
    if (idx >= 20 * 256) return;
    int k = idx >> 8, c = idx & 255;
    Bt[idx] = (c < 128) ? Wl[c * IN_DIM + k] : Wr[(c - 128) * IN_DIM + k];
}
__global__ void k_prepB2(const float* __restrict__ Wl, const float* __restrict__ Wr,
                         float* __restrict__ Bt) {
    int idx = blockIdx.x * 256 + threadIdx.x;
    if (idx >= 128 * 128) return;
    int k = idx >> 7, c = idx & 127;
    Bt[idx] = (c < 64) ? Wl[c * HC1 + k] : Wr[(c - 64) * HC1 + k];
}

// ================= layer-1 GEMM: [N x 20] @ Bt1 -> xlh|xrh fp16 =================
__global__ __launch_bounds__(256) void k_gemm1(
        const float* __restrict__ x, const float* __restrict__ Bt,
        const float* __restrict__ bl, const float* __restrict__ br,
        _Float16* __restrict__ xlh, _Float16* __restrict__ xrh) {
    __shared__ float sA[64 * IN_DIM];
    __shared__ float sB[IN_DIM * 256];
    int nb = blockIdx.x * 64;
    int tid = threadIdx.x;
    {
        size_t base = (size_t)nb * IN_DIM;
        size_t maxf = (size_t)NNODES * IN_DIM;
        for (int f = tid * 4; f < 64 * IN_DIM; f += 1024) {
            float4 v;
            if (base + f + 4 <= maxf) v = *(const float4*)(x + base + f);
            else                      v = *(const float4*)(x + maxf - 4);
            *(float4*)(sA + f) = v;
        }
    }
    for (int f = tid * 4; f < IN_DIM * 256; f += 1024)
        *(float4*)(sB + f) = *(const float4*)(Bt + f);
    __syncthreads();

    int tn = tid & 7, tc = tid >> 3;
    float acc[8][8];
    #pragma unroll
    for (int i = 0; i < 8; ++i)
        #pragma unroll
        for (int c = 0; c < 8; ++c) acc[i][c] = 0.0f;

    #pragma unroll
    for (int kt = 0; kt < 5; ++kt) {
        float4 a[8], b0[4], b1[4];
        #pragma unroll
        for (int i = 0; i < 8; ++i)
            a[i] = *(const float4*)(sA + (tn + 8 * i) * IN_DIM + kt * 4);
        #pragma unroll
        for (int j = 0; j < 4; ++j) {
            b0[j] = *(const float4*)(sB + (kt * 4 + j) * 256 + tc * 8);
            b1[j] = *(const float4*)(sB + (kt * 4 + j) * 256 + tc * 8 + 4);
        }
        #pragma unroll
        for (int i = 0; i < 8; ++i) {
            const float* ap = (const float*)&a[i];
            #pragma unroll
            for (int j = 0; j < 4; ++j) {
                float av = ap[j];
                const float* p0 = (const float*)&b0[j];
                const float* p1 = (const float*)&b1[j];
                #pragma unroll
                for (int c = 0; c < 4; ++c) {
                    acc[i][c]     += av * p0[c];
                    acc[i][c + 4] += av * p1[c];
                }
            }
        }
    }
    int c0 = tc * 8;
    float4 bias0, bias1;
    if (c0 < 128) {
        bias0 = *(const float4*)(bl + c0);
        bias1 = *(const float4*)(bl + c0 + 4);
    } else {
        bias0 = *(const float4*)(br + c0 - 128);
        bias1 = *(const float4*)(br + c0 - 124);
    }
    const float* q0 = (const float*)&bias0;
    const float* q1 = (const float*)&bias1;
    #pragma unroll
    for (int i = 0; i < 8; ++i) {
        int n = nb + tn + 8 * i;
        if (n >= NNODES) continue;
        float w[8];
        #pragma unroll
        for (int c = 0; c < 4; ++c) { w[c] = acc[i][c] + q0[c]; w[c + 4] = acc[i][c + 4] + q1[c]; }
        U4H ph;
        #pragma unroll
        for (int c = 0; c < 4; ++c) {
            h2 t; t.x = (_Float16)w[2 * c]; t.y = (_Float16)w[2 * c + 1];
            ph.h[c] = t;
        }
        if (c0 < 128) *(uint4*)(xlh + (size_t)n * HC1 + c0)       = ph.u;
        else          *(uint4*)(xrh + (size_t)n * HC1 + c0 - 128) = ph.u;
    }
}

// ================= layer-2 GEMM: [N x 128] @ Bt2 -> xl2h|xr2h fp16 ============
__global__ __launch_bounds__(256) void k_gemm2(
        const float* __restrict__ h1, const float* __restrict__ Bt,
        const float* __restrict__ bl, const float* __restrict__ br,
        _Float16* __restrict__ xl2h, _Float16* __restrict__ xr2h) {
    __shared__ float sA[64 * 132];
    __shared__ float sB[32 * 128];
    int nb = blockIdx.x * 64;
    int tid = threadIdx.x;
    for (int f = tid * 4; f < 64 * HC1; f += 1024) {
        int node = f >> 7, k = f & 127;
        int gn = nb + node; if (gn >= NNODES) gn = NNODES - 1;
        float4 v = *(const float4*)(h1 + (size_t)gn * HC1 + k);
        *(float4*)(sA + node * 132 + k) = v;
    }
    int tn = tid & 7, tc = tid >> 3;
    float acc[8][4];
    #pragma unroll
    for (int i = 0; i < 8; ++i)
        #pragma unroll
        for (int c = 0; c < 4; ++c) acc[i][c] = 0.0f;

    for (int kc = 0; kc < 4; ++kc) {
        __syncthreads();
        for (int f = tid * 4; f < 32 * 128; f += 1024)
            *(float4*)(sB + f) = *(const float4*)(Bt + kc * 4096 + f);
        __syncthreads();
        #pragma unroll
        for (int ks = 0; ks < 8; ++ks) {
            int k0 = kc * 32 + ks * 4;
            float4 a[8], b[4];
            #pragma unroll
            for (int i = 0; i < 8; ++i)
                a[i] = *(const float4*)(sA + (tn + 8 * i) * 132 + k0);
            #pragma unroll
            for (int j = 0; j < 4; ++j)
                b[j] = *(const float4*)(sB + (ks * 4 + j) * 128 + tc * 4);
            #pragma unroll
            for (int i = 0; i < 8; ++i) {
                const float* ap = (const float*)&a[i];
                #pragma unroll
                for (int j = 0; j < 4; ++j) {
                    float av = ap[j];
                    const float* bp = (const float*)&b[j];
                    #pragma unroll
                    for (int c = 0; c < 4; ++c) acc[i][c] += av * bp[c];
                }
            }
        }
    }
    int c0 = tc * 4;
    float4 bias;
    if (c0 < 64) bias = *(const float4*)(bl + c0);
    else         bias = *(const float4*)(br + c0 - 64);
    const float* q = (const float*)&bias;
    #pragma unroll
    for (int i = 0; i < 8; ++i) {
        int n = nb + tn + 8 * i;
        if (n >= NNODES) continue;
        float w[4];
        #pragma unroll
        for (int c = 0; c < 4; ++c) w[c] = acc[i][c] + q[c];
        U2H ph;
        h2 t0; t0.x = (_Float16)w[0]; t0.y = (_Float16)w[1];
        h2 t1; t1.x = (_Float16)w[2]; t1.y = (_Float16)w[3];
        ph.h[0] = t0; ph.h[1] = t1;
        if (c0 < 64) *(uint2*)(xl2h + (size_t)n * OUTC + c0)      = ph.u;
        else         *(uint2*)(xr2h + (size_t)n * OUTC + c0 - 64) = ph.u;
    }
}

// ===== fused per-node edge kernels: packed-f16 dot, no-max softmax ============
// layer 1: 1 wave/node, 4 edge-groups x 16 lanes; lane = 8 channels (head = q>>2)
__global__ __launch_bounds__(256) void k_node1(
        const int* __restrict__ rowptr, const int2* __restrict__ cedge,
        const float* __restrict__ easum,
        const _Float16* __restrict__ xlh, const _Float16* __restrict__ xrh,
        const float* __restrict__ We, const float* __restrict__ att,
        const float* __restrict__ bias, float* __restrict__ h1) {
    int n = blockIdx.x * 4 + (threadIdx.x >> 6);
    if (n >= NNODES) return;
    int lane = threadIdx.x & 63;
    int g = lane >> 4;        // edge slot 0..3
    int q = lane & 15;        // channel oct; head = q>>2
    int c = q * 8;
    U4H xru; xru.u = *(const uint4*)(xrh + (size_t)n * HC1 + c);
    float4 wf0 = *(const float4*)(We + c),  wf1 = *(const float4*)(We + c + 4);
    float4 af0 = *(const float4*)(att + c), af1 = *(const float4*)(att + c + 4);
    h2 we2[4], at2[4];
    we2[0].x = (_Float16)wf0.x; we2[0].y = (_Float16)wf0.y;
    we2[1].x = (_Float16)wf0.z; we2[1].y = (_Float16)wf0.w;
    we2[2].x = (_Float16)wf1.x; we2[2].y = (_Float16)wf1.y;
    we2[3].x = (_Float16)wf1.z; we2[3].y = (_Float16)wf1.w;
    at2[0].x = (_Float16)af0.x; at2[0].y = (_Float16)af0.y;
    at2[1].x = (_Float16)af0.z; at2[1].y = (_Float16)af0.w;
    at2[2].x = (_Float16)af1.x; at2[2].y = (_Float16)af1.y;
    at2[3].x = (_Float16)af1.z; at2[3].y = (_Float16)af1.w;
    h2 neg2; neg2.x = (_Float16)NEG; neg2.y = (_Float16)NEG;
    float s = 0.0f;
    float acc[8];
    #pragma unroll
    for (int k = 0; k < 8; ++k) acc[k] = 0.0f;
    int start = rowptr[n], end = rowptr[n + 1];
    int total = end - start + 1;                 // + virtual self edge
    float amean = easum[0] * (1.0f / (float)NEDGES);
    for (int base = 0; base < total; base += 4) {
        int o = base + g;
        int idx = start + o;
        int idxc = idx < NEDGES - 1 ? idx : NEDGES - 1;
        int2 ep = cedge[idxc];
        bool self  = (idx >= end);               // self-loop slot (or padding)
        bool valid = (o < total);
        int src = self ? n : ep.x;
        float a = self ? amean : __int_as_float(ep.y);
        U4H xsu; xsu.u = *(const uint4*)(xlh + (size_t)src * HC1 + c);
        h2 a2; a2.x = (_Float16)a; a2.y = a2.x;
        h2 lacc;
        {
            h2 e = xsu.h[0] + a2 * we2[0] + xru.h[0];
            h2 l = __builtin_elementwise_max(e, neg2 * e);
            lacc = l * at2[0];
        }
        #pragma unroll
        for (int j = 1; j < 4; ++j) {
            h2 e = xsu.h[j] + a2 * we2[j] + xru.h[j];
            h2 l = __builtin_elementwise_max(e, neg2 * e);
            lacc += l * at2[j];
        }
        // reduce logit over the head's 4-lane quad
        #pragma unroll
        for (int sh = 1; sh <= 2; sh <<= 1) {
            int lv = __builtin_bit_cast(int, lacc);
            int t = __shfl_xor(lv, sh, 64);
            lacc += __builtin_bit_cast(h2, t);
        }
        float p = (float)lacc.x + (float)lacc.y;
        float pe = valid ? __expf(p) : 0.0f;     // logits are O(1): no max needed
        s += pe;
        acc[0] += pe * (float)xsu.h[0].x; acc[1] += pe * (float)xsu.h[0].y;
        acc[2] += pe * (float)xsu.h[1].x; acc[3] += pe * (float)xsu.h[1].y;
        acc[4] += pe * (float)xsu.h[2].x; acc[5] += pe * (float)xsu.h[2].y;
        acc[6] += pe * (float)xsu.h[3].x; acc[7] += pe * (float)xsu.h[3].y;
    }
    // merge the 4 edge-groups: plain sums (no rescale needed)
    #pragma unroll
    for (int off = 16; off <= 32; off <<= 1) {
        s += __shfl_xor(s, off, 64);
        #pragma unroll
        for (int k = 0; k < 8; ++k) acc[k] += __shfl_xor(acc[k], off, 64);
    }
    if (g == 0) {
        float inv = 1.0f / s;
        float4 bi0 = *(const float4*)(bias + c), bi1 = *(const float4*)(bias + c + 4);
        const float* bq0 = (const float*)&bi0;
        const float* bq1 = (const float*)&bi1;
        float o[8];
        #pragma unroll
        for (int k = 0; k < 4; ++k) { o[k] = acc[k] * inv + bq0[k]; o[k + 4] = acc[k + 4] * inv + bq1[k]; }
        #pragma unroll
        for (int k = 0; k < 8; ++k) o[k] = o[k] > 0.0f ? o[k] : expm1f(o[k]);   // ELU
        float4 o0 = make_float4(o[0], o[1], o[2], o[3]);
        float4 o1 = make_float4(o[4], o[5], o[6], o[7]);
        float4* op = (float4*)(h1 + (size_t)n * HC1 + c);
        op[0] = o0; op[1] = o1;
    }
}

// layer 2: 1 wave/node, 8 edge-groups x 8 lanes; lane = 8 channels (single head)
__global__ __launch_bounds__(256) void k_node2(
        const int* __restrict__ rowptr, const int2* __restrict__ cedge,
        const float* __restrict__ easum,
        const _Float16* __restrict__ xl2h, const _Float16* __restrict__ xr2h,
        const float* __restrict__ We, const float* __restrict__ att,
        const float* __restrict__ bias, float* __restrict__ out) {
    int n = blockIdx.x * 4 + (threadIdx.x >> 6);
    if (n >= NNODES) return;
    int lane = threadIdx.x & 63;
    int g = lane >> 3;        // edge slot 0..7
    int q = lane & 7;         // channel oct
    int c = q * 8;
    U4H xru; xru.u = *(const uint4*)(xr2h + (size_t)n * OUTC + c);
    float4 wf0 = *(const float4*)(We + c),  wf1 = *(const float4*)(We + c + 4);
    float4 af0 = *(const float4*)(att + c), af1 = *(const float4*)(att + c + 4);
    h2 we2[4], at2[4];
    we2[0].x = (_Float16)wf0.x; we2[0].y = (_Float16)wf0.y;
    we2[1].x = (_Float16)wf0.z; we2[1].y = (_Float16)wf0.w;
    we2[2].x = (_Float16)wf1.x; we2[2].y = (_Float16)wf1.y;
    we2[3].x = (_Float16)wf1.z; we2[3].y = (_Float16)wf1.w;
    at2[0].x = (_Float16)af0.x; at2[0].y = (_Float16)af0.y;
    at2[1].x = (_Float16)af0.z; at2[1].y = (_Float16)af0.w;
    at2[2].x = (_Float16)af1.x; at2[2].y = (_Float16)af1.y;
    at2[3].x = (_Float16)af1.z; at2[3].y = (_Float16)af1.w;
    h2 neg2; neg2.x = (_Float16)NEG; neg2.y = (_Float16)NEG;
    float s = 0.0f;
    float acc[8];
    #pragma unroll
    for (int k = 0; k < 8; ++k) acc[k] = 0.0f;
    int start = rowptr[n], end = rowptr[n + 1];
    int total = end - start + 1;
    float amean = easum[0] * (1.0f / (float)NEDGES);
    for (int base = 0; base < total; base += 8) {
        int o = base + g;
        int idx = start + o;
        int idxc = idx < NEDGES - 1 ? idx : NEDGES - 1;
        int2 ep = cedge[idxc];
        bool self  = (idx >= end);
        bool valid = (o < total);
        int src = self ? n : ep.x;
        float a = self ? amean : __int_as_float(ep.y);
        U4H xsu; xsu.u = *(const uint4*)(xl2h + (size_t)src * OUTC + c);
        h2 a2; a2.x = (_Float16)a; a2.y = a2.x;
        h2 lacc;
        {
            h2 e = xsu.h[0] + a2 * we2[0] + xru.h[0];
            h2 l = __builtin_elementwise_max(e, neg2 * e);
            lacc = l * at2[0];
        }
        #pragma unroll
        for (int j = 1; j < 4; ++j) {
            h2 e = xsu.h[j] + a2 * we2[j] + xru.h[j];
            h2 l = __builtin_elementwise_max(e, neg2 * e);
            lacc += l * at2[j];
        }
        // reduce logit over the 8-lane group
        #pragma unroll
        for (int sh = 1; sh <= 4; sh <<= 1) {
            int lv = __builtin_bit_cast(int, lacc);
            int t = __shfl_xor(lv, sh, 64);
            lacc += __builtin_bit_cast(h2, t);
        }
        float p = (float)lacc.x + (float)lacc.y;
        float pe = valid ? __expf(p) : 0.0f;
        s += pe;
        acc[0] += pe * (float)xsu.h[0].x; acc[1] += pe * (float)xsu.h[0].y;
        acc[2] += pe * (float)xsu.h[1].x; acc[3] += pe * (float)xsu.h[1].y;
        acc[4] += pe * (float)xsu.h[2].x; acc[5] += pe * (float)xsu.h[2].y;
        acc[6] += pe * (float)xsu.h[3].x; acc[7] += pe * (float)xsu.h[3].y;
    }
    #pragma unroll
    for (int off = 8; off <= 32; off <<= 1) {
        s += __shfl_xor(s, off, 64);
        #pragma unroll
        for (int k = 0; k < 8; ++k) acc[k] += __shfl_xor(acc[k], off, 64);
    }
    if (g == 0) {
        float inv = 1.0f / s;
        float4 bi0 = *(const float4*)(bias + c), bi1 = *(const float4*)(bias + c + 4);
        const float* bq0 = (const float*)&bi0;
        const float* bq1 = (const float*)&bi1;
        float4 o0, o1;
        o0.x = acc[0] * inv + bq0[0];  o0.y = acc[1] * inv + bq0[1];
        o0.z = acc[2] * inv + bq0[2];  o0.w = acc[3] * inv + bq0[3];
        o1.x = acc[4] * inv + bq1[0];  o1.y = acc[5] * inv + bq1[1];
        o1.z = acc[6] * inv + bq1[2];  o1.w = acc[7] * inv + bq1[3];
        float4* op = (float4*)(out + (size_t)n * OUTC + c);
        op[0] = o0; op[1] = o1;
    }
}

extern "C" void kernel_launch(void* const* d_in, const int* in_sizes, int n_in,
                              void* d_out, int out_size, void* d_ws, size_t ws_size,
                              hipStream_t stream) {
    (void)in_sizes; (void)n_in; (void)out_size; (void)ws_size;
    const float* x    = (const float*)d_in[0];
    const int*   ei   = (const int*)d_in[1];
    const float* ea   = (const float*)d_in[2];
    const float* Wl1  = (const float*)d_in[3];
    const float* bl1  = (const float*)d_in[4];
    const float* Wr1  = (const float*)d_in[5];
    const float* br1  = (const float*)d_in[6];
    const float* We1  = (const float*)d_in[7];
    const float* att1 = (const float*)d_in[8];
    const float* b1   = (const float*)d_in[9];
    const float* Wl2  = (const float*)d_in[10];
    const float* bl2  = (const float*)d_in[11];
    const float* Wr2  = (const float*)d_in[12];
    const float* br2  = (const float*)d_in[13];
    const float* We2  = (const float*)d_in[14];
    const float* att2 = (const float*)d_in[15];
    const float* b2   = (const float*)d_in[16];
    float* out = (float*)d_out;

    // ---- workspace layout (bytes) ----
    char* wsb = (char*)d_ws;
    _Float16* xlh  = (_Float16*)wsb; wsb += (size_t)NNODES * HC1 * 2;   // 25.6 MB
    _Float16* xrh  = (_Float16*)wsb; wsb += (size_t)NNODES * HC1 * 2;
    float*  h1     = (float*)wsb;    wsb += (size_t)NNODES * HC1 * 4;   // 51.2 MB
    int2*   cedge  = (int2*)wsb;     wsb += (size_t)NEDGES * 8;         // 12.8 MB
    int*    cnt    = (int*)wsb;      wsb += (size_t)NNODES * 4;
    int*    rowptr = (int*)wsb;      wsb += (size_t)(NNODES + 1) * 4;
    int*    fill   = (int*)wsb;      wsb += (size_t)NNODES * 4;
    int*    csums  = (int*)wsb;      wsb += 512 * 4;
    float*  easum  = (float*)wsb;    wsb += 16;
    float*  Bt1    = (float*)wsb;    wsb += 20 * 256 * 4;
    float*  Bt2    = (float*)wsb;    wsb += 128 * 128 * 4;
    _Float16* xl2h = xlh;   // layer-2 tables reuse layer-1 storage (N*64 halves each)
    _Float16* xr2h = xrh;

    hipMemsetAsync(easum, 0, sizeof(float), stream);
    hipMemsetAsync(cnt,  0, (size_t)NNODES * 4, stream);
    hipMemsetAsync(fill, 0, (size_t)NNODES * 4, stream);

    // ---- CSR build + weight prep ----
    k_sum<<<256, 256, 0, stream>>>(ea, NEDGES, easum);
    k_hist<<<(NEDGES + 255) / 256, 256, 0, stream>>>(ei, cnt);
    k_prepB1<<<(20 * 256 + 255) / 256, 256, 0, stream>>>(Wl1, Wr1, Bt1);
    k_prepB2<<<(128 * 128 + 255) / 256, 256, 0, stream>>>(Wl2, Wr2, Bt2);
    k_scan_chunk<<<NCHUNK, 256, 0, stream>>>(cnt, rowptr, csums);
    k_scan_tops<<<1, 512, 0, stream>>>(csums);
    k_scan_add<<<NCHUNK, 256, 0, stream>>>(rowptr, csums);
    k_scatter<<<(NEDGES + 255) / 256, 256, 0, stream>>>(ei, ea, rowptr, fill, cedge);

    // ---- layer 1 ----
    k_gemm1<<<NBLK, 256, 0, stream>>>(x, Bt1, bl1, br1, xlh, xrh);
    k_node1<<<(NNODES + 3) / 4, 256, 0, stream>>>(rowptr, cedge, easum,
                                                  xlh, xrh, We1, att1, b1, h1);

    // ---- layer 2 ----
    k_gemm2<<<NBLK, 256, 0, stream>>>(h1, Bt2, bl2, br2, xl2h, xr2h);
    k_node2<<<(NNODES + 3) / 4, 256, 0, stream>>>(rowptr, cedge, easum,
                                                  xl2h, xr2h, We2, att2, b2, out);
}

// Round 7
// 476.105 us; speedup vs baseline: 39.4402x; 1.1466x over previous
//
#include <hip/hip_runtime.h>
#include <cstdint>
#include <cstddef>

#define NNODES 100000
#define NEDGES 1600000
#define IN_DIM 20
#define HID    32
#define HEADS  4
#define HC1    128
#define OUTC   64
#define NEG    0.2f
#define LOG2E  1.4426950408889634f
#define NCHUNK ((NNODES + 255) / 256)   // 391
#define NBLK   ((NNODES + 63) / 64)     // 1563

// clang-native packed half: arithmetic lowers to v_pk_*_f16
typedef _Float16 h2 __attribute__((ext_vector_type(2)));
union U4H { uint4 u; h2 h[4]; };
union U2H { uint2 u; h2 h[2]; };

// ---- sum of edge_attr (for self-loop fill value) ----
__global__ void k_sum(const float* __restrict__ ea, int n, float* __restrict__ out) {
    float s = 0.0f;
    for (int i = blockIdx.x * blockDim.x + threadIdx.x; i < n; i += gridDim.x * blockDim.x)
        s += ea[i];
    #pragma unroll
    for (int off = 32; off > 0; off >>= 1) s += __shfl_down(s, off, 64);
    __shared__ float ls[4];
    int lane = threadIdx.x & 63, wid = threadIdx.x >> 6;
    if (lane == 0) ls[wid] = s;
    __syncthreads();
    if (threadIdx.x == 0) {
        float t = ls[0] + ls[1] + ls[2] + ls[3];
        atomicAdd(out, t);
    }
}

// ================= CSR build (by destination) =================
// hist also records each edge's rank within its dst bucket -> scatter is atomic-free
__global__ void k_hist(const int* __restrict__ ei, int* __restrict__ cnt,
                       int* __restrict__ erank) {
    int e = blockIdx.x * blockDim.x + threadIdx.x;
    if (e < NEDGES) erank[e] = atomicAdd(&cnt[ei[NEDGES + e]], 1);
}

__global__ void k_scan_chunk(const int* __restrict__ cnt, int* __restrict__ rowptr,
                             int* __restrict__ csums) {
    __shared__ int s[256];
    int i = blockIdx.x * 256 + threadIdx.x;
    int v = (i < NNODES) ? cnt[i] : 0;
    s[threadIdx.x] = v;
    __syncthreads();
    for (int off = 1; off < 256; off <<= 1) {
        int t = (threadIdx.x >= off) ? s[threadIdx.x - off] : 0;
        __syncthreads();
        s[threadIdx.x] += t;
        __syncthreads();
    }
    if (i < NNODES) rowptr[i] = s[threadIdx.x] - v;
    if (threadIdx.x == 255) csums[blockIdx.x] = s[255];
}

__global__ void k_scan_tops(int* __restrict__ csums) {
    __shared__ int s[512];
    int v = (threadIdx.x < NCHUNK) ? csums[threadIdx.x] : 0;
    s[threadIdx.x] = v;
    __syncthreads();
    for (int off = 1; off < 512; off <<= 1) {
        int t = (threadIdx.x >= off) ? s[threadIdx.x - off] : 0;
        __syncthreads();
        s[threadIdx.x] += t;
        __syncthreads();
    }
    if (threadIdx.x < NCHUNK) csums[threadIdx.x] = s[threadIdx.x] - v;
}

__global__ void k_scan_add(int* __restrict__ rowptr, const int* __restrict__ csums) {
    int i = blockIdx.x * 256 + threadIdx.x;
    if (i < NNODES) rowptr[i] += csums[blockIdx.x];
    if (i == 0) rowptr[NNODES] = NEDGES;
}

__global__ void k_scatter(const int* __restrict__ ei, const float* __restrict__ ea,
                          const int* __restrict__ rowptr, const int* __restrict__ erank,
                          int2* __restrict__ cedge) {
    int e = blockIdx.x * blockDim.x + threadIdx.x;
    if (e >= NEDGES) return;
    int dst = ei[NEDGES + e];
    int pos = rowptr[dst] + erank[e];
    cedge[pos] = make_int2(ei[e], __float_as_int(ea[e]));
}

// ================= weight prep =================
__global__ void k_prepB1(const float* __restrict__ Wl, const float* __restrict__ Wr,
                         float* __restrict__ Bt) {
    int idx = blockIdx.x * 256 + threadIdx.x;
    if (idx >= 20 * 256) return;
    int k = idx >> 8, c = idx & 255;
    Bt[idx] = (c < 128) ? Wl[c * IN_DIM + k] : Wr[(c - 128) * IN_DIM + k];
}
__global__ void k_prepB2(const float* __restrict__ Wl, const float* __restrict__ Wr,
                         float* __restrict__ Bt) {
    int idx = blockIdx.x * 256 + threadIdx.x;
    if (idx >= 128 * 128) return;
    int k = idx >> 7, c = idx & 127;
    Bt[idx] = (c < 64) ? Wl[c * HC1 + k] : Wr[(c - 64) * HC1 + k];
}

// ================= layer-1 GEMM: [N x 20] @ Bt1 -> xlh|xrh fp16 =================
__global__ __launch_bounds__(256) void k_gemm1(
        const float* __restrict__ x, const float* __restrict__ Bt,
        const float* __restrict__ bl, const float* __restrict__ br,
        _Float16* __restrict__ xlh, _Float16* __restrict__ xrh) {
    __shared__ float sA[64 * IN_DIM];
    __shared__ float sB[IN_DIM * 256];
    int nb = blockIdx.x * 64;
    int tid = threadIdx.x;
    {
        size_t base = (size_t)nb * IN_DIM;
        size_t maxf = (size_t)NNODES * IN_DIM;
        for (int f = tid * 4; f < 64 * IN_DIM; f += 1024) {
            float4 v;
            if (base + f + 4 <= maxf) v = *(const float4*)(x + base + f);
            else                      v = *(const float4*)(x + maxf - 4);
            *(float4*)(sA + f) = v;
        }
    }
    for (int f = tid * 4; f < IN_DIM * 256; f += 1024)
        *(float4*)(sB + f) = *(const float4*)(Bt + f);
    __syncthreads();

    int tn = tid & 7, tc = tid >> 3;
    float acc[8][8];
    #pragma unroll
    for (int i = 0; i < 8; ++i)
        #pragma unroll
        for (int c = 0; c < 8; ++c) acc[i][c] = 0.0f;

    #pragma unroll
    for (int kt = 0; kt < 5; ++kt) {
        float4 a[8], b0[4], b1[4];
        #pragma unroll
        for (int i = 0; i < 8; ++i)
            a[i] = *(const float4*)(sA + (tn + 8 * i) * IN_DIM + kt * 4);
        #pragma unroll
        for (int j = 0; j < 4; ++j) {
            b0[j] = *(const float4*)(sB + (kt * 4 + j) * 256 + tc * 8);
            b1[j] = *(const float4*)(sB + (kt * 4 + j) * 256 + tc * 8 + 4);
        }
        #pragma unroll
        for (int i = 0; i < 8; ++i) {
            const float* ap = (const float*)&a[i];
            #pragma unroll
            for (int j = 0; j < 4; ++j) {
                float av = ap[j];
                const float* p0 = (const float*)&b0[j];
                const float* p1 = (const float*)&b1[j];
                #pragma unroll
                for (int c = 0; c < 4; ++c) {
                    acc[i][c]     += av * p0[c];
                    acc[i][c + 4] += av * p1[c];
                }
            }
        }
    }
    int c0 = tc * 8;
    float4 bias0, bias1;
    if (c0 < 128) {
        bias0 = *(const float4*)(bl + c0);
        bias1 = *(const float4*)(bl + c0 + 4);
    } else {
        bias0 = *(const float4*)(br + c0 - 128);
        bias1 = *(const float4*)(br + c0 - 124);
    }
    const float* q0 = (const float*)&bias0;
    const float* q1 = (const float*)&bias1;
    #pragma unroll
    for (int i = 0; i < 8; ++i) {
        int n = nb + tn + 8 * i;
        if (n >= NNODES) continue;
        float w[8];
        #pragma unroll
        for (int c = 0; c < 4; ++c) { w[c] = acc[i][c] + q0[c]; w[c + 4] = acc[i][c + 4] + q1[c]; }
        U4H ph;
        #pragma unroll
        for (int c = 0; c < 4; ++c) {
            h2 t; t.x = (_Float16)w[2 * c]; t.y = (_Float16)w[2 * c + 1];
            ph.h[c] = t;
        }
        if (c0 < 128) *(uint4*)(xlh + (size_t)n * HC1 + c0)       = ph.u;
        else          *(uint4*)(xrh + (size_t)n * HC1 + c0 - 128) = ph.u;
    }
}

// ================= layer-2 GEMM: h1(fp16) @ Bt2 -> xl2h|xr2h fp16 ============
__global__ __launch_bounds__(256) void k_gemm2(
        const _Float16* __restrict__ h1h, const float* __restrict__ Bt,
        const float* __restrict__ bl, const float* __restrict__ br,
        _Float16* __restrict__ xl2h, _Float16* __restrict__ xr2h) {
    __shared__ float sA[64 * 132];
    __shared__ float sB[32 * 128];
    int nb = blockIdx.x * 64;
    int tid = threadIdx.x;
    for (int idx = tid * 8; idx < 64 * HC1; idx += 2048) {
        int node = idx >> 7, k = idx & 127;
        int gn = nb + node; if (gn >= NNODES) gn = NNODES - 1;
        U4H v; v.u = *(const uint4*)(h1h + ((size_t)gn << 7) + k);
        float4 f0, f1;
        f0.x = (float)v.h[0].x; f0.y = (float)v.h[0].y;
        f0.z = (float)v.h[1].x; f0.w = (float)v.h[1].y;
        f1.x = (float)v.h[2].x; f1.y = (float)v.h[2].y;
        f1.z = (float)v.h[3].x; f1.w = (float)v.h[3].y;
        *(float4*)(sA + node * 132 + k)     = f0;
        *(float4*)(sA + node * 132 + k + 4) = f1;
    }
    int tn = tid & 7, tc = tid >> 3;
    float acc[8][4];
    #pragma unroll
    for (int i = 0; i < 8; ++i)
        #pragma unroll
        for (int c = 0; c < 4; ++c) acc[i][c] = 0.0f;

    for (int kc = 0; kc < 4; ++kc) {
        __syncthreads();
        for (int f = tid * 4; f < 32 * 128; f += 1024)
            *(float4*)(sB + f) = *(const float4*)(Bt + kc * 4096 + f);
        __syncthreads();
        #pragma unroll
        for (int ks = 0; ks < 8; ++ks) {
            int k0 = kc * 32 + ks * 4;
            float4 a[8], b[4];
            #pragma unroll
            for (int i = 0; i < 8; ++i)
                a[i] = *(const float4*)(sA + (tn + 8 * i) * 132 + k0);
            #pragma unroll
            for (int j = 0; j < 4; ++j)
                b[j] = *(const float4*)(sB + (ks * 4 + j) * 128 + tc * 4);
            #pragma unroll
            for (int i = 0; i < 8; ++i) {
                const float* ap = (const float*)&a[i];
                #pragma unroll
                for (int j = 0; j < 4; ++j) {
                    float av = ap[j];
                    const float* bp = (const float*)&b[j];
                    #pragma unroll
                    for (int c = 0; c < 4; ++c) acc[i][c] += av * bp[c];
                }
            }
        }
    }
    int c0 = tc * 4;
    float4 bias;
    if (c0 < 64) bias = *(const float4*)(bl + c0);
    else         bias = *(const float4*)(br + c0 - 64);
    const float* q = (const float*)&bias;
    #pragma unroll
    for (int i = 0; i < 8; ++i) {
        int n = nb + tn + 8 * i;
        if (n >= NNODES) continue;
        float w[4];
        #pragma unroll
        for (int c = 0; c < 4; ++c) w[c] = acc[i][c] + q[c];
        U2H ph;
        h2 t0; t0.x = (_Float16)w[0]; t0.y = (_Float16)w[1];
        h2 t1; t1.x = (_Float16)w[2]; t1.y = (_Float16)w[3];
        ph.h[0] = t0; ph.h[1] = t1;
        if (c0 < 64) *(uint2*)(xl2h + (size_t)n * OUTC + c0)      = ph.u;
        else         *(uint2*)(xr2h + (size_t)n * OUTC + c0 - 64) = ph.u;
    }
}

// ===== fused per-node edge kernels: packed-f16 dot, exp2 softmax, self hoisted =====
// layer 1: 1 wave/node, 4 edge-groups x 16 lanes; lane = 8 channels (head = q>>2)
__global__ __launch_bounds__(256) void k_node1(
        const int* __restrict__ rowptr, const int2* __restrict__ cedge,
        const float* __restrict__ easum,
        const _Float16* __restrict__ xlh, const _Float16* __restrict__ xrh,
        const float* __restrict__ We, const float* __restrict__ att,
        const float* __restrict__ bias, _Float16* __restrict__ h1h) {
    int n = blockIdx.x * 4 + (threadIdx.x >> 6);
    if (n >= NNODES) return;
    int lane = threadIdx.x & 63;
    int g = lane >> 4;        // edge slot 0..3
    int q = lane & 15;        // channel oct; head = q>>2
    int c = q * 8;
    U4H xru; xru.u = *(const uint4*)(xrh + ((unsigned)n << 7) + c);
    float4 wf0 = *(const float4*)(We + c),  wf1 = *(const float4*)(We + c + 4);
    float4 af0 = *(const float4*)(att + c), af1 = *(const float4*)(att + c + 4);
    h2 we2[4], at2[4];
    we2[0].x = (_Float16)wf0.x; we2[0].y = (_Float16)wf0.y;
    we2[1].x = (_Float16)wf0.z; we2[1].y = (_Float16)wf0.w;
    we2[2].x = (_Float16)wf1.x; we2[2].y = (_Float16)wf1.y;
    we2[3].x = (_Float16)wf1.z; we2[3].y = (_Float16)wf1.w;
    at2[0].x = (_Float16)(af0.x * LOG2E); at2[0].y = (_Float16)(af0.y * LOG2E);
    at2[1].x = (_Float16)(af0.z * LOG2E); at2[1].y = (_Float16)(af0.w * LOG2E);
    at2[2].x = (_Float16)(af1.x * LOG2E); at2[2].y = (_Float16)(af1.y * LOG2E);
    at2[3].x = (_Float16)(af1.z * LOG2E); at2[3].y = (_Float16)(af1.w * LOG2E);
    h2 neg2; neg2.x = (_Float16)NEG; neg2.y = (_Float16)NEG;
    float s = 0.0f;
    float acc[8];
    #pragma unroll
    for (int k = 0; k < 8; ++k) acc[k] = 0.0f;
    int start = rowptr[n], end = rowptr[n + 1];
    int deg = end - start;

    // ---- self edge (prologue; only group 0 contributes) ----
    {
        U4H xss; xss.u = *(const uint4*)(xlh + ((unsigned)n << 7) + c);
        float amean = easum[0] * (1.0f / (float)NEDGES);
        h2 a2; a2.x = (_Float16)amean; a2.y = a2.x;
        h2 lacc;
        {
            h2 e = xss.h[0] + a2 * we2[0] + xru.h[0];
            lacc = __builtin_elementwise_max(e, neg2 * e) * at2[0];
        }
        #pragma unroll
        for (int j = 1; j < 4; ++j) {
            h2 e = xss.h[j] + a2 * we2[j] + xru.h[j];
            lacc += __builtin_elementwise_max(e, neg2 * e) * at2[j];
        }
        #pragma unroll
        for (int sh = 1; sh <= 2; sh <<= 1) {
            int lv = __builtin_bit_cast(int, lacc);
            int t = __shfl_xor(lv, sh, 64);
            lacc += __builtin_bit_cast(h2, t);
        }
        if (g == 0) {
            float pe = exp2f((float)lacc.x + (float)lacc.y);
            s += pe;
            acc[0] += pe * (float)xss.h[0].x; acc[1] += pe * (float)xss.h[0].y;
            acc[2] += pe * (float)xss.h[1].x; acc[3] += pe * (float)xss.h[1].y;
            acc[4] += pe * (float)xss.h[2].x; acc[5] += pe * (float)xss.h[2].y;
            acc[6] += pe * (float)xss.h[3].x; acc[7] += pe * (float)xss.h[3].y;
        }
    }

    // ---- main loop: 8 edges per iteration (2 unrolled groups of 4) ----
    for (int base = 0; base < deg; base += 8) {
        int oA = base + g, oB = oA + 4;
        int idxA = start + (oA < deg ? oA : deg - 1);
        int idxB = start + (oB < deg ? oB : deg - 1);
        int2 epA = cedge[idxA];
        int2 epB = cedge[idxB];
        bool vA = oA < deg, vB = oB < deg;
        int srcA = vA ? epA.x : n;
        int srcB = vB ? epB.x : n;
        U4H xsA; xsA.u = *(const uint4*)(xlh + ((unsigned)srcA << 7) + c);
        U4H xsB; xsB.u = *(const uint4*)(xlh + ((unsigned)srcB << 7) + c);
        // edge A
        {
            h2 a2; a2.x = (_Float16)__int_as_float(epA.y); a2.y = a2.x;
            h2 lacc;
            {
                h2 e = xsA.h[0] + a2 * we2[0] + xru.h[0];
                lacc = __builtin_elementwise_max(e, neg2 * e) * at2[0];
            }
            #pragma unroll
            for (int j = 1; j < 4; ++j) {
                h2 e = xsA.h[j] + a2 * we2[j] + xru.h[j];
                lacc += __builtin_elementwise_max(e, neg2 * e) * at2[j];
            }
            #pragma unroll
            for (int sh = 1; sh <= 2; sh <<= 1) {
                int lv = __builtin_bit_cast(int, lacc);
                int t = __shfl_xor(lv, sh, 64);
                lacc += __builtin_bit_cast(h2, t);
            }
            float pe = vA ? exp2f((float)lacc.x + (float)lacc.y) : 0.0f;
            s += pe;
            acc[0] += pe * (float)xsA.h[0].x; acc[1] += pe * (float)xsA.h[0].y;
            acc[2] += pe * (float)xsA.h[1].x; acc[3] += pe * (float)xsA.h[1].y;
            acc[4] += pe * (float)xsA.h[2].x; acc[5] += pe * (float)xsA.h[2].y;
            acc[6] += pe * (float)xsA.h[3].x; acc[7] += pe * (float)xsA.h[3].y;
        }
        // edge B
        {
            h2 a2; a2.x = (_Float16)__int_as_float(epB.y); a2.y = a2.x;
            h2 lacc;
            {
                h2 e = xsB.h[0] + a2 * we2[0] + xru.h[0];
                lacc = __builtin_elementwise_max(e, neg2 * e) * at2[0];
            }
            #pragma unroll
            for (int j = 1; j < 4; ++j) {
                h2 e = xsB.h[j] + a2 * we2[j] + xru.h[j];
                lacc += __builtin_elementwise_max(e, neg2 * e) * at2[j];
            }
            #pragma unroll
            for (int sh = 1; sh <= 2; sh <<= 1) {
                int lv = __builtin_bit_cast(int, lacc);
                int t = __shfl_xor(lv, sh, 64);
                lacc += __builtin_bit_cast(h2, t);
            }
            float pe = vB ? exp2f((float)lacc.x + (float)lacc.y) : 0.0f;
            s += pe;
            acc[0] += pe * (float)xsB.h[0].x; acc[1] += pe * (float)xsB.h[0].y;
            acc[2] += pe * (float)xsB.h[1].x; acc[3] += pe * (float)xsB.h[1].y;
            acc[4] += pe * (float)xsB.h[2].x; acc[5] += pe * (float)xsB.h[2].y;
            acc[6] += pe * (float)xsB.h[3].x; acc[7] += pe * (float)xsB.h[3].y;
        }
    }
    // merge the 4 edge-groups (plain sums; softmax shift-free)
    #pragma unroll
    for (int off = 16; off <= 32; off <<= 1) {
        s += __shfl_xor(s, off, 64);
        #pragma unroll
        for (int k = 0; k < 8; ++k) acc[k] += __shfl_xor(acc[k], off, 64);
    }
    if (g == 0) {
        float inv = 1.0f / s;
        float4 bi0 = *(const float4*)(bias + c), bi1 = *(const float4*)(bias + c + 4);
        const float* bq0 = (const float*)&bi0;
        const float* bq1 = (const float*)&bi1;
        float o[8];
        #pragma unroll
        for (int k = 0; k < 4; ++k) { o[k] = acc[k] * inv + bq0[k]; o[k + 4] = acc[k + 4] * inv + bq1[k]; }
        #pragma unroll
        for (int k = 0; k < 8; ++k) o[k] = o[k] > 0.0f ? o[k] : expm1f(o[k]);   // ELU
        U4H ph;
        #pragma unroll
        for (int k = 0; k < 4; ++k) {
            h2 t; t.x = (_Float16)o[2 * k]; t.y = (_Float16)o[2 * k + 1];
            ph.h[k] = t;
        }
        *(uint4*)(h1h + ((unsigned)n << 7) + c) = ph.u;
    }
}

// layer 2: 1 wave/node, 8 edge-groups x 8 lanes; lane = 8 channels (single head)
__global__ __launch_bounds__(256) void k_node2(
        const int* __restrict__ rowptr, const int2* __restrict__ cedge,
        const float* __restrict__ easum,
        const _Float16* __restrict__ xl2h, const _Float16* __restrict__ xr2h,
        const float* __restrict__ We, const float* __restrict__ att,
        const float* __restrict__ bias, float* __restrict__ out) {
    int n = blockIdx.x * 4 + (threadIdx.x >> 6);
    if (n >= NNODES) return;
    int lane = threadIdx.x & 63;
    int g = lane >> 3;        // edge slot 0..7
    int q = lane & 7;         // channel oct
    int c = q * 8;
    U4H xru; xru.u = *(const uint4*)(xr2h + ((unsigned)n << 6) + c);
    float4 wf0 = *(const float4*)(We + c),  wf1 = *(const float4*)(We + c + 4);
    float4 af0 = *(const float4*)(att + c), af1 = *(const float4*)(att + c + 4);
    h2 we2[4], at2[4];
    we2[0].x = (_Float16)wf0.x; we2[0].y = (_Float16)wf0.y;
    we2[1].x = (_Float16)wf0.z; we2[1].y = (_Float16)wf0.w;
    we2[2].x = (_Float16)wf1.x; we2[2].y = (_Float16)wf1.y;
    we2[3].x = (_Float16)wf1.z; we2[3].y = (_Float16)wf1.w;
    at2[0].x = (_Float16)(af0.x * LOG2E); at2[0].y = (_Float16)(af0.y * LOG2E);
    at2[1].x = (_Float16)(af0.z * LOG2E); at2[1].y = (_Float16)(af0.w * LOG2E);
    at2[2].x = (_Float16)(af1.x * LOG2E); at2[2].y = (_Float16)(af1.y * LOG2E);
    at2[3].x = (_Float16)(af1.z * LOG2E); at2[3].y = (_Float16)(af1.w * LOG2E);
    h2 neg2; neg2.x = (_Float16)NEG; neg2.y = (_Float16)NEG;
    float s = 0.0f;
    float acc[8];
    #pragma unroll
    for (int k = 0; k < 8; ++k) acc[k] = 0.0f;
    int start = rowptr[n], end = rowptr[n + 1];
    int deg = end - start;

    // ---- self edge ----
    {
        U4H xss; xss.u = *(const uint4*)(xl2h + ((unsigned)n << 6) + c);
        float amean = easum[0] * (1.0f / (float)NEDGES);
        h2 a2; a2.x = (_Float16)amean; a2.y = a2.x;
        h2 lacc;
        {
            h2 e = xss.h[0] + a2 * we2[0] + xru.h[0];
            lacc = __builtin_elementwise_max(e, neg2 * e) * at2[0];
        }
        #pragma unroll
        for (int j = 1; j < 4; ++j) {
            h2 e = xss.h[j] + a2 * we2[j] + xru.h[j];
            lacc += __builtin_elementwise_max(e, neg2 * e) * at2[j];
        }
        #pragma unroll
        for (int sh = 1; sh <= 4; sh <<= 1) {
            int lv = __builtin_bit_cast(int, lacc);
            int t = __shfl_xor(lv, sh, 64);
            lacc += __builtin_bit_cast(h2, t);
        }
        if (g == 0) {
            float pe = exp2f((float)lacc.x + (float)lacc.y);
            s += pe;
            acc[0] += pe * (float)xss.h[0].x; acc[1] += pe * (float)xss.h[0].y;
            acc[2] += pe * (float)xss.h[1].x; acc[3] += pe * (float)xss.h[1].y;
            acc[4] += pe * (float)xss.h[2].x; acc[5] += pe * (float)xss.h[2].y;
            acc[6] += pe * (float)xss.h[3].x; acc[7] += pe * (float)xss.h[3].y;
        }
    }

    // ---- main loop: 8 edges per iteration ----
    for (int base = 0; base < deg; base += 8) {
        int o = base + g;
        int idx = start + (o < deg ? o : deg - 1);
        int2 ep = cedge[idx];
        bool valid = o < deg;
        int src = valid ? ep.x : n;
        U4H xsu; xsu.u = *(const uint4*)(xl2h + ((unsigned)src << 6) + c);
        h2 a2; a2.x = (_Float16)__int_as_float(ep.y); a2.y = a2.x;
        h2 lacc;
        {
            h2 e = xsu.h[0] + a2 * we2[0] + xru.h[0];
            lacc = __builtin_elementwise_max(e, neg2 * e) * at2[0];
        }
        #pragma unroll
        for (int j = 1; j < 4; ++j) {
            h2 e = xsu.h[j] + a2 * we2[j] + xru.h[j];
            lacc += __builtin_elementwise_max(e, neg2 * e) * at2[j];
        }
        #pragma unroll
        for (int sh = 1; sh <= 4; sh <<= 1) {
            int lv = __builtin_bit_cast(int, lacc);
            int t = __shfl_xor(lv, sh, 64);
            lacc += __builtin_bit_cast(h2, t);
        }
        float pe = valid ? exp2f((float)lacc.x + (float)lacc.y) : 0.0f;
        s += pe;
        acc[0] += pe * (float)xsu.h[0].x; acc[1] += pe * (float)xsu.h[0].y;
        acc[2] += pe * (float)xsu.h[1].x; acc[3] += pe * (float)xsu.h[1].y;
        acc[4] += pe * (float)xsu.h[2].x; acc[5] += pe * (float)xsu.h[2].y;
        acc[6] += pe * (float)xsu.h[3].x; acc[7] += pe * (float)xsu.h[3].y;
    }
    #pragma unroll
    for (int off = 8; off <= 32; off <<= 1) {
        s += __shfl_xor(s, off, 64);
        #pragma unroll
        for (int k = 0; k < 8; ++k) acc[k] += __shfl_xor(acc[k], off, 64);
    }
    if (g == 0) {
        float inv = 1.0f / s;
        float4 bi0 = *(const float4*)(bias + c), bi1 = *(const float4*)(bias + c + 4);
        const float* bq0 = (const float*)&bi0;
        const float* bq1 = (const float*)&bi1;
        float4 o0, o1;
        o0.x = acc[0] * inv + bq0[0];  o0.y = acc[1] * inv + bq0[1];
        o0.z = acc[2] * inv + bq0[2];  o0.w = acc[3] * inv + bq0[3];
        o1.x = acc[4] * inv + bq1[0];  o1.y = acc[5] * inv + bq1[1];
        o1.z = acc[6] * inv + bq1[2];  o1.w = acc[7] * inv + bq1[3];
        float4* op = (float4*)(out + (size_t)n * OUTC + c);
        op[0] = o0; op[1] = o1;
    }
}

extern "C" void kernel_launch(void* const* d_in, const int* in_sizes, int n_in,
                              void* d_out, int out_size, void* d_ws, size_t ws_size,
                              hipStream_t stream) {
    (void)in_sizes; (void)n_in; (void)out_size; (void)ws_size;
    const float* x    = (const float*)d_in[0];
    const int*   ei   = (const int*)d_in[1];
    const float* ea   = (const float*)d_in[2];
    const float* Wl1  = (const float*)d_in[3];
    const float* bl1  = (const float*)d_in[4];
    const float* Wr1  = (const float*)d_in[5];
    const float* br1  = (const float*)d_in[6];
    const float* We1  = (const float*)d_in[7];
    const float* att1 = (const float*)d_in[8];
    const float* b1   = (const float*)d_in[9];
    const float* Wl2  = (const float*)d_in[10];
    const float* bl2  = (const float*)d_in[11];
    const float* Wr2  = (const float*)d_in[12];
    const float* br2  = (const float*)d_in[13];
    const float* We2  = (const float*)d_in[14];
    const float* att2 = (const float*)d_in[15];
    const float* b2   = (const float*)d_in[16];
    float* out = (float*)d_out;

    // ---- workspace layout (bytes) ----
    char* wsb = (char*)d_ws;
    _Float16* xlh  = (_Float16*)wsb; wsb += (size_t)NNODES * HC1 * 2;   // 25.6 MB
    _Float16* xrh  = (_Float16*)wsb; wsb += (size_t)NNODES * HC1 * 2;
    _Float16* h1h  = (_Float16*)wsb; wsb += (size_t)NNODES * HC1 * 2;   // 25.6 MB (fp16 now)
    int2*   cedge  = (int2*)wsb;     wsb += (size_t)NEDGES * 8;         // 12.8 MB
    int*    erank  = (int*)wsb;      wsb += (size_t)NEDGES * 4;         // 6.4 MB
    int*    cnt    = (int*)wsb;      wsb += (size_t)NNODES * 4;
    int*    rowptr = (int*)wsb;      wsb += (size_t)(NNODES + 1) * 4;
    int*    csums  = (int*)wsb;      wsb += 512 * 4;
    float*  easum  = (float*)wsb;    wsb += 16;
    float*  Bt1    = (float*)wsb;    wsb += 20 * 256 * 4;
    float*  Bt2    = (float*)wsb;    wsb += 128 * 128 * 4;
    _Float16* xl2h = xlh;   // layer-2 tables reuse layer-1 storage (N*64 halves each)
    _Float16* xr2h = xrh;

    hipMemsetAsync(easum, 0, sizeof(float), stream);
    hipMemsetAsync(cnt, 0, (size_t)NNODES * 4, stream);

    // ---- CSR build + weight prep ----
    k_sum<<<256, 256, 0, stream>>>(ea, NEDGES, easum);
    k_hist<<<(NEDGES + 255) / 256, 256, 0, stream>>>(ei, cnt, erank);
    k_prepB1<<<(20 * 256 + 255) / 256, 256, 0, stream>>>(Wl1, Wr1, Bt1);
    k_prepB2<<<(128 * 128 + 255) / 256, 256, 0, stream>>>(Wl2, Wr2, Bt2);
    k_scan_chunk<<<NCHUNK, 256, 0, stream>>>(cnt, rowptr, csums);
    k_scan_tops<<<1, 512, 0, stream>>>(csums);
    k_scan_add<<<NCHUNK, 256, 0, stream>>>(rowptr, csums);
    k_scatter<<<(NEDGES + 255) / 256, 256, 0, stream>>>(ei, ea, rowptr, erank, cedge);

    // ---- layer 1 ----
    k_gemm1<<<NBLK, 256, 0, stream>>>(x, Bt1, bl1, br1, xlh, xrh);
    k_node1<<<(NNODES + 3) / 4, 256, 0, stream>>>(rowptr, cedge, easum,
                                                  xlh, xrh, We1, att1, b1, h1h);

    // ---- layer 2 ----
    k_gemm2<<<NBLK, 256, 0, stream>>>(h1h, Bt2, bl2, br2, xl2h, xr2h);
    k_node2<<<(NNODES + 3) / 4, 256, 0, stream>>>(rowptr, cedge, easum,
                                                  xl2h, xr2h, We2, att2, b2, out);
}

// Round 8
// 446.054 us; speedup vs baseline: 42.0973x; 1.0674x over previous
//
#include <hip/hip_runtime.h>
#include <cstdint>
#include <cstddef>

#define NNODES 100000
#define NEDGES 1600000
#define IN_DIM 20
#define HID    32
#define HEADS  4
#define HC1    128
#define OUTC   64
#define NEG    0.2f
#define LOG2E  1.4426950408889634f
#define NCHUNK ((NNODES + 255) / 256)   // 391
#define NBLK   ((NNODES + 63) / 64)     // 1563

// clang-native packed half: arithmetic lowers to v_pk_*_f16
typedef _Float16 h2 __attribute__((ext_vector_type(2)));
union U4H { uint4 u; h2 h[4]; };
union U2H { uint2 u; h2 h[2]; };

// ---- sum of edge_attr (for self-loop fill value) ----
__global__ void k_sum(const float* __restrict__ ea, int n, float* __restrict__ out) {
    float s = 0.0f;
    for (int i = blockIdx.x * blockDim.x + threadIdx.x; i < n; i += gridDim.x * blockDim.x)
        s += ea[i];
    #pragma unroll
    for (int off = 32; off > 0; off >>= 1) s += __shfl_down(s, off, 64);
    __shared__ float ls[4];
    int lane = threadIdx.x & 63, wid = threadIdx.x >> 6;
    if (lane == 0) ls[wid] = s;
    __syncthreads();
    if (threadIdx.x == 0) {
        float t = ls[0] + ls[1] + ls[2] + ls[3];
        atomicAdd(out, t);
    }
}

// ================= CSR build (by destination) =================
__global__ void k_hist(const int* __restrict__ ei, int* __restrict__ cnt,
                       int* __restrict__ erank) {
    int e = blockIdx.x * blockDim.x + threadIdx.x;
    if (e < NEDGES) erank[e] = atomicAdd(&cnt[ei[NEDGES + e]], 1);
}

__global__ void k_scan_chunk(const int* __restrict__ cnt, int* __restrict__ rowptr,
                             int* __restrict__ csums) {
    __shared__ int s[256];
    int i = blockIdx.x * 256 + threadIdx.x;
    int v = (i < NNODES) ? cnt[i] : 0;
    s[threadIdx.x] = v;
    __syncthreads();
    for (int off = 1; off < 256; off <<= 1) {
        int t = (threadIdx.x >= off) ? s[threadIdx.x - off] : 0;
        __syncthreads();
        s[threadIdx.x] += t;
        __syncthreads();
    }
    if (i < NNODES) rowptr[i] = s[threadIdx.x] - v;
    if (threadIdx.x == 255) csums[blockIdx.x] = s[255];
}

__global__ void k_scan_tops(int* __restrict__ csums) {
    __shared__ int s[512];
    int v = (threadIdx.x < NCHUNK) ? csums[threadIdx.x] : 0;
    s[threadIdx.x] = v;
    __syncthreads();
    for (int off = 1; off < 512; off <<= 1) {
        int t = (threadIdx.x >= off) ? s[threadIdx.x - off] : 0;
        __syncthreads();
        s[threadIdx.x] += t;
        __syncthreads();
    }
    if (threadIdx.x < NCHUNK) csums[threadIdx.x] = s[threadIdx.x] - v;
}

__global__ void k_scan_add(int* __restrict__ rowptr, const int* __restrict__ csums) {
    int i = blockIdx.x * 256 + threadIdx.x;
    if (i < NNODES) rowptr[i] += csums[blockIdx.x];
    if (i == 0) rowptr[NNODES] = NEDGES;
}

__global__ void k_scatter(const int* __restrict__ ei, const float* __restrict__ ea,
                          const int* __restrict__ rowptr, const int* __restrict__ erank,
                          int2* __restrict__ cedge) {
    int e = blockIdx.x * blockDim.x + threadIdx.x;
    if (e >= NEDGES) return;
    int dst = ei[NEDGES + e];
    int pos = rowptr[dst] + erank[e];
    cedge[pos] = make_int2(ei[e], __float_as_int(ea[e]));
}

// ================= fused prep: Bt2 | Bt1 | packed fp16 We/att =================
__global__ void k_prep(const float* __restrict__ Wl1, const float* __restrict__ Wr1,
                       float* __restrict__ Bt1,
                       const float* __restrict__ Wl2, const float* __restrict__ Wr2,
                       float* __restrict__ Bt2,
                       const float* __restrict__ We1, const float* __restrict__ att1,
                       _Float16* __restrict__ Weh1, _Float16* __restrict__ Ath1,
                       const float* __restrict__ We2, const float* __restrict__ att2,
                       _Float16* __restrict__ Weh2, _Float16* __restrict__ Ath2) {
    int idx = blockIdx.x * 256 + threadIdx.x;
    if (idx < 16384) {
        int k = idx >> 7, c = idx & 127;
        Bt2[idx] = (c < 64) ? Wl2[c * HC1 + k] : Wr2[(c - 64) * HC1 + k];
    }
    int i1 = idx - 16384;
    if (i1 >= 0 && i1 < 5120) {
        int k = i1 >> 8, c = i1 & 255;
        Bt1[i1] = (c < 128) ? Wl1[c * IN_DIM + k] : Wr1[(c - 128) * IN_DIM + k];
    }
    int i2 = idx - (16384 + 5120);
    if (i2 >= 0 && i2 < 128) {
        Weh1[i2] = (_Float16)We1[i2];
        Ath1[i2] = (_Float16)(att1[i2] * LOG2E);
    }
    int i3 = idx - (16384 + 5120 + 128);
    if (i3 >= 0 && i3 < 64) {
        Weh2[i3] = (_Float16)We2[i3];
        Ath2[i3] = (_Float16)(att2[i3] * LOG2E);
    }
}

// ================= layer-1 GEMM: [N x 20] @ Bt1 -> xlh|xrh fp16 =================
__global__ __launch_bounds__(256) void k_gemm1(
        const float* __restrict__ x, const float* __restrict__ Bt,
        const float* __restrict__ bl, const float* __restrict__ br,
        _Float16* __restrict__ xlh, _Float16* __restrict__ xrh) {
    __shared__ float sA[64 * IN_DIM];
    __shared__ float sB[IN_DIM * 256];
    int nb = blockIdx.x * 64;
    int tid = threadIdx.x;
    {
        size_t base = (size_t)nb * IN_DIM;
        size_t maxf = (size_t)NNODES * IN_DIM;
        for (int f = tid * 4; f < 64 * IN_DIM; f += 1024) {
            float4 v;
            if (base + f + 4 <= maxf) v = *(const float4*)(x + base + f);
            else                      v = *(const float4*)(x + maxf - 4);
            *(float4*)(sA + f) = v;
        }
    }
    for (int f = tid * 4; f < IN_DIM * 256; f += 1024)
        *(float4*)(sB + f) = *(const float4*)(Bt + f);
    __syncthreads();

    int tn = tid & 7, tc = tid >> 3;
    float acc[8][8];
    #pragma unroll
    for (int i = 0; i < 8; ++i)
        #pragma unroll
        for (int c = 0; c < 8; ++c) acc[i][c] = 0.0f;

    #pragma unroll
    for (int kt = 0; kt < 5; ++kt) {
        float4 a[8], b0[4], b1[4];
        #pragma unroll
        for (int i = 0; i < 8; ++i)
            a[i] = *(const float4*)(sA + (tn + 8 * i) * IN_DIM + kt * 4);
        #pragma unroll
        for (int j = 0; j < 4; ++j) {
            b0[j] = *(const float4*)(sB + (kt * 4 + j) * 256 + tc * 8);
            b1[j] = *(const float4*)(sB + (kt * 4 + j) * 256 + tc * 8 + 4);
        }
        #pragma unroll
        for (int i = 0; i < 8; ++i) {
            const float* ap = (const float*)&a[i];
            #pragma unroll
            for (int j = 0; j < 4; ++j) {
                float av = ap[j];
                const float* p0 = (const float*)&b0[j];
                const float* p1 = (const float*)&b1[j];
                #pragma unroll
                for (int c = 0; c < 4; ++c) {
                    acc[i][c]     += av * p0[c];
                    acc[i][c + 4] += av * p1[c];
                }
            }
        }
    }
    int c0 = tc * 8;
    float4 bias0, bias1;
    if (c0 < 128) {
        bias0 = *(const float4*)(bl + c0);
        bias1 = *(const float4*)(bl + c0 + 4);
    } else {
        bias0 = *(const float4*)(br + c0 - 128);
        bias1 = *(const float4*)(br + c0 - 124);
    }
    const float* q0 = (const float*)&bias0;
    const float* q1 = (const float*)&bias1;
    #pragma unroll
    for (int i = 0; i < 8; ++i) {
        int n = nb + tn + 8 * i;
        if (n >= NNODES) continue;
        float w[8];
        #pragma unroll
        for (int c = 0; c < 4; ++c) { w[c] = acc[i][c] + q0[c]; w[c + 4] = acc[i][c + 4] + q1[c]; }
        U4H ph;
        #pragma unroll
        for (int c = 0; c < 4; ++c) {
            h2 t; t.x = (_Float16)w[2 * c]; t.y = (_Float16)w[2 * c + 1];
            ph.h[c] = t;
        }
        if (c0 < 128) *(uint4*)(xlh + (size_t)n * HC1 + c0)       = ph.u;
        else          *(uint4*)(xrh + (size_t)n * HC1 + c0 - 128) = ph.u;
    }
}

// ================= layer-2 GEMM: h1(fp16) @ Bt2 -> xl2h|xr2h fp16 ============
__global__ __launch_bounds__(256) void k_gemm2(
        const _Float16* __restrict__ h1h, const float* __restrict__ Bt,
        const float* __restrict__ bl, const float* __restrict__ br,
        _Float16* __restrict__ xl2h, _Float16* __restrict__ xr2h) {
    __shared__ float sA[64 * 132];
    __shared__ float sB[32 * 128];
    int nb = blockIdx.x * 64;
    int tid = threadIdx.x;
    for (int idx = tid * 8; idx < 64 * HC1; idx += 2048) {
        int node = idx >> 7, k = idx & 127;
        int gn = nb + node; if (gn >= NNODES) gn = NNODES - 1;
        U4H v; v.u = *(const uint4*)(h1h + ((size_t)gn << 7) + k);
        float4 f0, f1;
        f0.x = (float)v.h[0].x; f0.y = (float)v.h[0].y;
        f0.z = (float)v.h[1].x; f0.w = (float)v.h[1].y;
        f1.x = (float)v.h[2].x; f1.y = (float)v.h[2].y;
        f1.z = (float)v.h[3].x; f1.w = (float)v.h[3].y;
        *(float4*)(sA + node * 132 + k)     = f0;
        *(float4*)(sA + node * 132 + k + 4) = f1;
    }
    int tn = tid & 7, tc = tid >> 3;
    float acc[8][4];
    #pragma unroll
    for (int i = 0; i < 8; ++i)
        #pragma unroll
        for (int c = 0; c < 4; ++c) acc[i][c] = 0.0f;

    for (int kc = 0; kc < 4; ++kc) {
        __syncthreads();
        for (int f = tid * 4; f < 32 * 128; f += 1024)
            *(float4*)(sB + f) = *(const float4*)(Bt + kc * 4096 + f);
        __syncthreads();
        #pragma unroll
        for (int ks = 0; ks < 8; ++ks) {
            int k0 = kc * 32 + ks * 4;
            float4 a[8], b[4];
            #pragma unroll
            for (int i = 0; i < 8; ++i)
                a[i] = *(const float4*)(sA + (tn + 8 * i) * 132 + k0);
            #pragma unroll
            for (int j = 0; j < 4; ++j)
                b[j] = *(const float4*)(sB + (ks * 4 + j) * 128 + tc * 4);
            #pragma unroll
            for (int i = 0; i < 8; ++i) {
                const float* ap = (const float*)&a[i];
                #pragma unroll
                for (int j = 0; j < 4; ++j) {
                    float av = ap[j];
                    const float* bp = (const float*)&b[j];
                    #pragma unroll
                    for (int c = 0; c < 4; ++c) acc[i][c] += av * bp[c];
                }
            }
        }
    }
    int c0 = tc * 4;
    float4 bias;
    if (c0 < 64) bias = *(const float4*)(bl + c0);
    else         bias = *(const float4*)(br + c0 - 64);
    const float* q = (const float*)&bias;
    #pragma unroll
    for (int i = 0; i < 8; ++i) {
        int n = nb + tn + 8 * i;
        if (n >= NNODES) continue;
        float w[4];
        #pragma unroll
        for (int c = 0; c < 4; ++c) w[c] = acc[i][c] + q[c];
        U2H ph;
        h2 t0; t0.x = (_Float16)w[0]; t0.y = (_Float16)w[1];
        h2 t1; t1.x = (_Float16)w[2]; t1.y = (_Float16)w[3];
        ph.h[0] = t0; ph.h[1] = t1;
        if (c0 < 64) *(uint2*)(xl2h + (size_t)n * OUTC + c0)      = ph.u;
        else         *(uint2*)(xr2h + (size_t)n * OUTC + c0 - 64) = ph.u;
    }
}

// ===== fused per-node edge kernels: packed-f16 dot + fp16 accumulators ========
// layer 1: 1 wave/node, 4 edge-groups x 16 lanes; lane = 8 channels (head = q>>2)
__global__ __launch_bounds__(256) void k_node1(
        const int* __restrict__ rowptr, const int2* __restrict__ cedge,
        const float* __restrict__ easum,
        const _Float16* __restrict__ xlh, const _Float16* __restrict__ xrh,
        const _Float16* __restrict__ Weh, const _Float16* __restrict__ Ath,
        const float* __restrict__ bias, _Float16* __restrict__ h1h) {
    int n = blockIdx.x * 4 + (threadIdx.x >> 6);
    if (n >= NNODES) return;
    int lane = threadIdx.x & 63;
    int g = lane >> 4;        // edge slot 0..3
    int q = lane & 15;        // channel oct; head = q>>2
    int c = q * 8;
    U4H xru; xru.u = *(const uint4*)(xrh + ((unsigned)n << 7) + c);
    U4H weu; weu.u = *(const uint4*)(Weh + c);
    U4H atu; atu.u = *(const uint4*)(Ath + c);
    h2 neg2; neg2.x = (_Float16)NEG; neg2.y = neg2.x;
    h2 zero; zero.x = (_Float16)0; zero.y = zero.x;
    h2 acc2[4] = { zero, zero, zero, zero };
    float s = 0.0f;
    int start = rowptr[n], deg = rowptr[n + 1] - start;

    // ---- self edge (prologue; only group 0 contributes) ----
    {
        U4H xss; xss.u = *(const uint4*)(xlh + ((unsigned)n << 7) + c);
        float amean = easum[0] * (1.0f / (float)NEDGES);
        h2 a2; a2.x = (_Float16)amean; a2.y = a2.x;
        h2 lacc;
        {
            h2 e = xss.h[0] + (a2 * weu.h[0] + xru.h[0]);
            lacc = __builtin_elementwise_max(e, neg2 * e) * atu.h[0];
        }
        #pragma unroll
        for (int j = 1; j < 4; ++j) {
            h2 e = xss.h[j] + (a2 * weu.h[j] + xru.h[j]);
            lacc += __builtin_elementwise_max(e, neg2 * e) * atu.h[j];
        }
        #pragma unroll
        for (int sh = 1; sh <= 2; sh <<= 1) {
            int lv = __builtin_bit_cast(int, lacc);
            int t = __shfl_xor(lv, sh, 64);
            lacc += __builtin_bit_cast(h2, t);
        }
        if (g == 0) {
            float pe = exp2f((float)lacc.x + (float)lacc.y);
            s += pe;
            h2 pe2; pe2.x = (_Float16)pe; pe2.y = pe2.x;
            #pragma unroll
            for (int j = 0; j < 4; ++j) acc2[j] += pe2 * xss.h[j];
        }
    }

    // ---- main loop: 8 edges/iter, edge descriptors prefetched 1 iter ahead ----
    if (deg > 0) {
        int2 epA = cedge[start + (g < deg ? g : deg - 1)];
        int2 epB = cedge[start + (4 + g < deg ? 4 + g : deg - 1)];
        for (int base = 0; base < deg; base += 8) {
            int2 cA = epA, cB = epB;
            int nxt = base + 8;
            if (nxt < deg) {
                epA = cedge[start + (nxt + g < deg ? nxt + g : deg - 1)];
                epB = cedge[start + (nxt + 4 + g < deg ? nxt + 4 + g : deg - 1)];
            }
            bool vA = base + g < deg, vB = base + 4 + g < deg;
            int srcA = vA ? cA.x : n;
            int srcB = vB ? cB.x : n;
            U4H xsA; xsA.u = *(const uint4*)(xlh + ((unsigned)srcA << 7) + c);
            U4H xsB; xsB.u = *(const uint4*)(xlh + ((unsigned)srcB << 7) + c);
            // edge A
            {
                h2 a2; a2.x = (_Float16)__int_as_float(cA.y); a2.y = a2.x;
                h2 lacc;
                {
                    h2 e = xsA.h[0] + (a2 * weu.h[0] + xru.h[0]);
                    lacc = __builtin_elementwise_max(e, neg2 * e) * atu.h[0];
                }
                #pragma unroll
                for (int j = 1; j < 4; ++j) {
                    h2 e = xsA.h[j] + (a2 * weu.h[j] + xru.h[j]);
                    lacc += __builtin_elementwise_max(e, neg2 * e) * atu.h[j];
                }
                #pragma unroll
                for (int sh = 1; sh <= 2; sh <<= 1) {
                    int lv = __builtin_bit_cast(int, lacc);
                    int t = __shfl_xor(lv, sh, 64);
                    lacc += __builtin_bit_cast(h2, t);
                }
                float pe = vA ? exp2f((float)lacc.x + (float)lacc.y) : 0.0f;
                s += pe;
                h2 pe2; pe2.x = (_Float16)pe; pe2.y = pe2.x;
                #pragma unroll
                for (int j = 0; j < 4; ++j) acc2[j] += pe2 * xsA.h[j];
            }
            // edge B
            {
                h2 a2; a2.x = (_Float16)__int_as_float(cB.y); a2.y = a2.x;
                h2 lacc;
                {
                    h2 e = xsB.h[0] + (a2 * weu.h[0] + xru.h[0]);
                    lacc = __builtin_elementwise_max(e, neg2 * e) * atu.h[0];
                }
                #pragma unroll
                for (int j = 1; j < 4; ++j) {
                    h2 e = xsB.h[j] + (a2 * weu.h[j] + xru.h[j]);
                    lacc += __builtin_elementwise_max(e, neg2 * e) * atu.h[j];
                }
                #pragma unroll
                for (int sh = 1; sh <= 2; sh <<= 1) {
                    int lv = __builtin_bit_cast(int, lacc);
                    int t = __shfl_xor(lv, sh, 64);
                    lacc += __builtin_bit_cast(h2, t);
                }
                float pe = vB ? exp2f((float)lacc.x + (float)lacc.y) : 0.0f;
                s += pe;
                h2 pe2; pe2.x = (_Float16)pe; pe2.y = pe2.x;
                #pragma unroll
                for (int j = 0; j < 4; ++j) acc2[j] += pe2 * xsB.h[j];
            }
        }
    }
    // merge the 4 edge-groups (plain sums; softmax shift-free)
    #pragma unroll
    for (int off = 16; off <= 32; off <<= 1) {
        s += __shfl_xor(s, off, 64);
        #pragma unroll
        for (int j = 0; j < 4; ++j) {
            int lv = __builtin_bit_cast(int, acc2[j]);
            int t = __shfl_xor(lv, off, 64);
            acc2[j] += __builtin_bit_cast(h2, t);
        }
    }
    if (g == 0) {
        float inv = 1.0f / s;
        float4 bi0 = *(const float4*)(bias + c), bi1 = *(const float4*)(bias + c + 4);
        const float* bq = (const float*)&bi0;
        const float* br_ = (const float*)&bi1;
        float o[8];
        #pragma unroll
        for (int j = 0; j < 4; ++j) {
            o[2 * j]     = (float)acc2[j].x * inv + (j < 2 ? bq[2 * j]     : br_[2 * j - 4]);
            o[2 * j + 1] = (float)acc2[j].y * inv + (j < 2 ? bq[2 * j + 1] : br_[2 * j - 3]);
        }
        #pragma unroll
        for (int k = 0; k < 8; ++k) o[k] = o[k] > 0.0f ? o[k] : expm1f(o[k]);   // ELU
        U4H ph;
        #pragma unroll
        for (int k = 0; k < 4; ++k) {
            h2 t; t.x = (_Float16)o[2 * k]; t.y = (_Float16)o[2 * k + 1];
            ph.h[k] = t;
        }
        *(uint4*)(h1h + ((unsigned)n << 7) + c) = ph.u;
    }
}

// layer 2: 1 wave/node, 8 edge-groups x 8 lanes; lane = 8 channels (single head)
__global__ __launch_bounds__(256) void k_node2(
        const int* __restrict__ rowptr, const int2* __restrict__ cedge,
        const float* __restrict__ easum,
        const _Float16* __restrict__ xl2h, const _Float16* __restrict__ xr2h,
        const _Float16* __restrict__ Weh, const _Float16* __restrict__ Ath,
        const float* __restrict__ bias, float* __restrict__ out) {
    int n = blockIdx.x * 4 + (threadIdx.x >> 6);
    if (n >= NNODES) return;
    int lane = threadIdx.x & 63;
    int g = lane >> 3;        // edge slot 0..7
    int q = lane & 7;         // channel oct
    int c = q * 8;
    U4H xru; xru.u = *(const uint4*)(xr2h + ((unsigned)n << 6) + c);
    U4H weu; weu.u = *(const uint4*)(Weh + c);
    U4H atu; atu.u = *(const uint4*)(Ath + c);
    h2 neg2; neg2.x = (_Float16)NEG; neg2.y = neg2.x;
    h2 zero; zero.x = (_Float16)0; zero.y = zero.x;
    h2 acc2[4] = { zero, zero, zero, zero };
    float s = 0.0f;
    int start = rowptr[n], deg = rowptr[n + 1] - start;

    // ---- self edge ----
    {
        U4H xss; xss.u = *(const uint4*)(xl2h + ((unsigned)n << 6) + c);
        float amean = easum[0] * (1.0f / (float)NEDGES);
        h2 a2; a2.x = (_Float16)amean; a2.y = a2.x;
        h2 lacc;
        {
            h2 e = xss.h[0] + (a2 * weu.h[0] + xru.h[0]);
            lacc = __builtin_elementwise_max(e, neg2 * e) * atu.h[0];
        }
        #pragma unroll
        for (int j = 1; j < 4; ++j) {
            h2 e = xss.h[j] + (a2 * weu.h[j] + xru.h[j]);
            lacc += __builtin_elementwise_max(e, neg2 * e) * atu.h[j];
        }
        #pragma unroll
        for (int sh = 1; sh <= 4; sh <<= 1) {
            int lv = __builtin_bit_cast(int, lacc);
            int t = __shfl_xor(lv, sh, 64);
            lacc += __builtin_bit_cast(h2, t);
        }
        if (g == 0) {
            float pe = exp2f((float)lacc.x + (float)lacc.y);
            s += pe;
            h2 pe2; pe2.x = (_Float16)pe; pe2.y = pe2.x;
            #pragma unroll
            for (int j = 0; j < 4; ++j) acc2[j] += pe2 * xss.h[j];
        }
    }

    // ---- main loop: 8 edges/iter, descriptors prefetched 1 iter ahead ----
    if (deg > 0) {
        int2 ep = cedge[start + (g < deg ? g : deg - 1)];
        for (int base = 0; base < deg; base += 8) {
            int2 cE = ep;
            int nxt = base + 8;
            if (nxt < deg)
                ep = cedge[start + (nxt + g < deg ? nxt + g : deg - 1)];
            bool valid = base + g < deg;
            int src = valid ? cE.x : n;
            U4H xsu; xsu.u = *(const uint4*)(xl2h + ((unsigned)src << 6) + c);
            h2 a2; a2.x = (_Float16)__int_as_float(cE.y); a2.y = a2.x;
            h2 lacc;
            {
                h2 e = xsu.h[0] + (a2 * weu.h[0] + xru.h[0]);
                lacc = __builtin_elementwise_max(e, neg2 * e) * atu.h[0];
            }
            #pragma unroll
            for (int j = 1; j < 4; ++j) {
                h2 e = xsu.h[j] + (a2 * weu.h[j] + xru.h[j]);
                lacc += __builtin_elementwise_max(e, neg2 * e) * atu.h[j];
            }
            #pragma unroll
            for (int sh = 1; sh <= 4; sh <<= 1) {
                int lv = __builtin_bit_cast(int, lacc);
                int t = __shfl_xor(lv, sh, 64);
                lacc += __builtin_bit_cast(h2, t);
            }
            float pe = valid ? exp2f((float)lacc.x + (float)lacc.y) : 0.0f;
            s += pe;
            h2 pe2; pe2.x = (_Float16)pe; pe2.y = pe2.x;
            #pragma unroll
            for (int j = 0; j < 4; ++j) acc2[j] += pe2 * xsu.h[j];
        }
    }
    #pragma unroll
    for (int off = 8; off <= 32; off <<= 1) {
        s += __shfl_xor(s, off, 64);
        #pragma unroll
        for (int j = 0; j < 4; ++j) {
            int lv = __builtin_bit_cast(int, acc2[j]);
            int t = __shfl_xor(lv, off, 64);
            acc2[j] += __builtin_bit_cast(h2, t);
        }
    }
    if (g == 0) {
        float inv = 1.0f / s;
        float4 bi0 = *(const float4*)(bias + c), bi1 = *(const float4*)(bias + c + 4);
        const float* bq0 = (const float*)&bi0;
        const float* bq1 = (const float*)&bi1;
        float4 o0, o1;
        o0.x = (float)acc2[0].x * inv + bq0[0];  o0.y = (float)acc2[0].y * inv + bq0[1];
        o0.z = (float)acc2[1].x * inv + bq0[2];  o0.w = (float)acc2[1].y * inv + bq0[3];
        o1.x = (float)acc2[2].x * inv + bq1[0];  o1.y = (float)acc2[2].y * inv + bq1[1];
        o1.z = (float)acc2[3].x * inv + bq1[2];  o1.w = (float)acc2[3].y * inv + bq1[3];
        float4* op = (float4*)(out + (size_t)n * OUTC + c);
        op[0] = o0; op[1] = o1;
    }
}

extern "C" void kernel_launch(void* const* d_in, const int* in_sizes, int n_in,
                              void* d_out, int out_size, void* d_ws, size_t ws_size,
                              hipStream_t stream) {
    (void)in_sizes; (void)n_in; (void)out_size; (void)ws_size;
    const float* x    = (const float*)d_in[0];
    const int*   ei   = (const int*)d_in[1];
    const float* ea   = (const float*)d_in[2];
    const float* Wl1  = (const float*)d_in[3];
    const float* bl1  = (const float*)d_in[4];
    const float* Wr1  = (const float*)d_in[5];
    const float* br1  = (const float*)d_in[6];
    const float* We1  = (const float*)d_in[7];
    const float* att1 = (const float*)d_in[8];
    const float* b1   = (const float*)d_in[9];
    const float* Wl2  = (const float*)d_in[10];
    const float* bl2  = (const float*)d_in[11];
    const float* Wr2  = (const float*)d_in[12];
    const float* br2  = (const float*)d_in[13];
    const float* We2  = (const float*)d_in[14];
    const float* att2 = (const float*)d_in[15];
    const float* b2   = (const float*)d_in[16];
    float* out = (float*)d_out;

    // ---- workspace layout (bytes; every region 16B-aligned) ----
    char* wsb = (char*)d_ws;
    _Float16* xlh  = (_Float16*)wsb; wsb += (size_t)NNODES * HC1 * 2;   // 25.6 MB
    _Float16* xrh  = (_Float16*)wsb; wsb += (size_t)NNODES * HC1 * 2;
    _Float16* h1h  = (_Float16*)wsb; wsb += (size_t)NNODES * HC1 * 2;
    int2*   cedge  = (int2*)wsb;     wsb += (size_t)NEDGES * 8;         // 12.8 MB
    int*    erank  = (int*)wsb;      wsb += (size_t)NEDGES * 4;         // 6.4 MB
    int*    cnt    = (int*)wsb;      wsb += (size_t)NNODES * 4;
    int*    rowptr = (int*)wsb;      wsb += ((size_t)(NNODES + 4) * 4); // padded to 16B
    int*    csums  = (int*)wsb;      wsb += 512 * 4;
    float*  easum  = (float*)wsb;    wsb += 16;
    float*  Bt1    = (float*)wsb;    wsb += 20 * 256 * 4;
    float*  Bt2    = (float*)wsb;    wsb += 128 * 128 * 4;
    _Float16* Weh1 = (_Float16*)wsb; wsb += 128 * 2;
    _Float16* Ath1 = (_Float16*)wsb; wsb += 128 * 2;
    _Float16* Weh2 = (_Float16*)wsb; wsb += 64 * 2;
    _Float16* Ath2 = (_Float16*)wsb; wsb += 64 * 2;
    _Float16* xl2h = xlh;   // layer-2 tables reuse layer-1 storage
    _Float16* xr2h = xrh;

    hipMemsetAsync(easum, 0, sizeof(float), stream);
    hipMemsetAsync(cnt, 0, (size_t)NNODES * 4, stream);

    // ---- CSR build + fused prep ----
    k_sum<<<256, 256, 0, stream>>>(ea, NEDGES, easum);
    k_hist<<<(NEDGES + 255) / 256, 256, 0, stream>>>(ei, cnt, erank);
    k_prep<<<(16384 + 5120 + 128 + 64 + 255) / 256, 256, 0, stream>>>(
        Wl1, Wr1, Bt1, Wl2, Wr2, Bt2, We1, att1, Weh1, Ath1, We2, att2, Weh2, Ath2);
    k_scan_chunk<<<NCHUNK, 256, 0, stream>>>(cnt, rowptr, csums);
    k_scan_tops<<<1, 512, 0, stream>>>(csums);
    k_scan_add<<<NCHUNK, 256, 0, stream>>>(rowptr, csums);
    k_scatter<<<(NEDGES + 255) / 256, 256, 0, stream>>>(ei, ea, rowptr, erank, cedge);

    // ---- layer 1 ----
    k_gemm1<<<NBLK, 256, 0, stream>>>(x, Bt1, bl1, br1, xlh, xrh);
    k_node1<<<(NNODES + 3) / 4, 256, 0, stream>>>(rowptr, cedge, easum,
                                                  xlh, xrh, Weh1, Ath1, b1, h1h);

    // ---- layer 2 ----
    k_gemm2<<<NBLK, 256, 0, stream>>>(h1h, Bt2, bl2, br2, xl2h, xr2h);
    k_node2<<<(NNODES + 3) / 4, 256, 0, stream>>>(rowptr, cedge, easum,
                                                  xl2h, xr2h, Weh2, Ath2, b2, out);
}